// Round 2
// baseline (198329.321 us; speedup 1.0000x reference)
//
#include <hip/hip_runtime.h>
#include <hip/hip_cooperative_groups.h>
#include <math.h>

#define D_IN  1024
#define H_DIM 2048
#define H3    6144
#define T_SEQ 4096
#define S_SEQ 4095

namespace cg = cooperative_groups;

// ---------------------------------------------------------------------------
// Tiled fp32 GEMM: C[M,N] = op(A)[M,K] @ B[N,K]^T + bias[N]
//   Atrans=1: A(m,k) = A[k*lda + m]   (gx: A = X, lda = T)
//   Atrans=0: A(m,k) = A[m*lda + k]   (yhat: A = log_h, lda = H)
// ---------------------------------------------------------------------------
#define TS 64
#define KS 16
#define LSTR 68

__global__ __launch_bounds__(256) void gemm_bias(
    const float* __restrict__ A, const float* __restrict__ B,
    const float* __restrict__ bias, float* __restrict__ C,
    int M, int N, int K, int lda, int Atrans)
{
    __shared__ __align__(16) float As[KS * LSTR];
    __shared__ __align__(16) float Bs[KS * LSTR];
    const int tid = threadIdx.x;
    const int m0 = blockIdx.x * TS;
    const int n0 = blockIdx.y * TS;
    const int tx = tid & 15, ty = tid >> 4;
    float c[4][4] = {};

    for (int k0 = 0; k0 < K; k0 += KS) {
        if (Atrans) {
            const int ml = tid & 63;
            const int kb = tid >> 6;
            #pragma unroll
            for (int kk = 0; kk < KS; kk += 4) {
                const int m = m0 + ml;
                As[(kk + kb) * LSTR + ml] =
                    (m < M) ? A[(size_t)(k0 + kk + kb) * lda + m] : 0.f;
            }
        } else {
            const int kl = tid & 15;
            const int mb = tid >> 4;
            #pragma unroll
            for (int ml = 0; ml < TS; ml += 16) {
                const int m = m0 + ml + mb;
                As[kl * LSTR + ml + mb] =
                    (m < M) ? A[(size_t)m * lda + (k0 + kl)] : 0.f;
            }
        }
        {
            const int kl = tid & 15;
            const int nb = tid >> 4;
            #pragma unroll
            for (int nl = 0; nl < TS; nl += 16) {
                Bs[kl * LSTR + nl + nb] = B[(size_t)(n0 + nl + nb) * K + (k0 + kl)];
            }
        }
        __syncthreads();
        #pragma unroll
        for (int kk = 0; kk < KS; ++kk) {
            const float4 a = *(const float4*)&As[kk * LSTR + tx * 4];
            const float4 b = *(const float4*)&Bs[kk * LSTR + ty * 4];
            c[0][0] += a.x * b.x; c[0][1] += a.x * b.y; c[0][2] += a.x * b.z; c[0][3] += a.x * b.w;
            c[1][0] += a.y * b.x; c[1][1] += a.y * b.y; c[1][2] += a.y * b.z; c[1][3] += a.y * b.w;
            c[2][0] += a.z * b.x; c[2][1] += a.z * b.y; c[2][2] += a.z * b.z; c[2][3] += a.z * b.w;
            c[3][0] += a.w * b.x; c[3][1] += a.w * b.y; c[3][2] += a.w * b.z; c[3][3] += a.w * b.w;
        }
        __syncthreads();
    }
    #pragma unroll
    for (int i = 0; i < 4; ++i) {
        const int m = m0 + tx * 4 + i;
        if (m < M) {
            #pragma unroll
            for (int j = 0; j < 4; ++j) {
                const int n = n0 + ty * 4 + j;
                C[(size_t)m * N + n] = c[i][j] + bias[n];
            }
        }
    }
}

// ---------------------------------------------------------------------------
// Convert W_h2h (fp32, [6144,2048] gate-major) to bf16, re-laid-out so that
// block b's 24 rows (units 8b..8b+7, r = jj*3+g -> global row 8b+jj+g*2048)
// are contiguous: wbf[((b*24 + r)*2048) + k].
// ---------------------------------------------------------------------------
__device__ inline unsigned short f2bf(float f) {
    union { float f; unsigned u; } a; a.f = f;
    unsigned u = a.u;
    u += 0x7fffu + ((u >> 16) & 1u);   // round-to-nearest-even
    return (unsigned short)(u >> 16);
}

__global__ __launch_bounds__(256) void conv_whh(
    const float* __restrict__ Whh, unsigned short* __restrict__ wbf)
{
    const int g = blockIdx.x * 256 + threadIdx.x;
    const size_t base = (size_t)g * 4;              // 4 elems per thread
    const int b   = (int)(base / 49152);            // 24*2048
    const int rem = (int)(base % 49152);
    const int r   = rem / 2048;
    const int k   = rem % 2048;
    const size_t srow = ((size_t)(8 * b + r / 3 + (r % 3) * H_DIM)) * H_DIM + k;
    const float4 v = *(const float4*)(Whh + srow);
    ushort4 o;
    o.x = f2bf(v.x); o.y = f2bf(v.y); o.z = f2bf(v.z); o.w = f2bf(v.w);
    *(ushort4*)(wbf + base) = o;
}

// ---------------------------------------------------------------------------
// Persistent cooperative scan. 256 blocks x 256 threads, 1 block/CU.
// Block b owns hidden units J = 8b..8b+7 (3 gate rows each, bf16 in LDS).
// Wave w computes units {2w, 2w+1}. One grid.sync per time step.
// ---------------------------------------------------------------------------
#define SMEM_SZ (24 * 2048 * 2 + 2048 * 4 + 96 * 4)

__global__ __launch_bounds__(256, 1) void gru_scan(
    const unsigned short* __restrict__ wbf, const float* __restrict__ bhh,
    const float* __restrict__ gx, const float* __restrict__ h0,
    float* __restrict__ log_h)
{
    cg::grid_group grid = cg::this_grid();
    extern __shared__ char smem[];
    unsigned short* wlds = (unsigned short*)smem;            // 24*2048 bf16
    float* hs  = (float*)(smem + 24 * 2048 * 2);             // 2048 fp32
    float* gxs = (float*)(smem + 24 * 2048 * 2 + 2048 * 4);  // 2 x 32
    float* bb  = gxs + 64;                                   // 24

    const int tid = threadIdx.x;
    const int b = blockIdx.x;
    const int w = tid >> 6, l = tid & 63;

    // Stage this block's weight slice into LDS (96 KB, coalesced 16B/lane).
    {
        const uint4* src = (const uint4*)(wbf + (size_t)b * 24 * 2048);
        uint4* dst = (uint4*)wlds;
        #pragma unroll
        for (int i = 0; i < 24; ++i) dst[tid + 256 * i] = src[tid + 256 * i];
    }
    for (int i = tid; i < H_DIM; i += 256) hs[i] = h0[i];
    if (tid < 24) {
        const int n = 8 * b + tid / 3 + (tid % 3) * H_DIM;
        bb[tid]  = bhh[n];
        gxs[tid] = gx[n];              // step-0 input gates (includes b_i2h)
    }
    __syncthreads();

    const int rbase = w * 6;
    for (int t = 0; t < S_SEQ; ++t) {
        // Prefetch next step's 24 gx values (consumed after next barrier).
        float gpre = 0.f;
        const bool pf = (tid < 24) && (t + 1 < S_SEQ);
        if (pf) gpre = gx[(size_t)(t + 1) * H3 + 8 * b + tid / 3 + (tid % 3) * H_DIM];

        // h chunk into registers: lane l covers k in [i*512 + l*8, +8).
        float4 hreg[8];
        const float4* hs4 = (const float4*)hs;
        #pragma unroll
        for (int i = 0; i < 4; ++i) {
            hreg[i * 2 + 0] = hs4[i * 128 + l * 2 + 0];
            hreg[i * 2 + 1] = hs4[i * 128 + l * 2 + 1];
        }

        // 6 row dots (bf16 weights, fp32 accumulate), full-wave butterfly.
        float sums[6];
        #pragma unroll
        for (int m = 0; m < 6; ++m) {
            const int r = rbase + m;
            const uint4* wrow = (const uint4*)wlds + r * 256;
            float a0 = 0.f, a1 = 0.f, a2 = 0.f, a3 = 0.f;
            #pragma unroll
            for (int i = 0; i < 4; ++i) {
                const uint4 u = wrow[i * 64 + l];
                const float4 hv0 = hreg[i * 2 + 0], hv1 = hreg[i * 2 + 1];
                a0 += __uint_as_float(u.x << 16)          * hv0.x;
                a1 += __uint_as_float(u.x & 0xffff0000u)  * hv0.y;
                a2 += __uint_as_float(u.y << 16)          * hv0.z;
                a3 += __uint_as_float(u.y & 0xffff0000u)  * hv0.w;
                a0 += __uint_as_float(u.z << 16)          * hv1.x;
                a1 += __uint_as_float(u.z & 0xffff0000u)  * hv1.y;
                a2 += __uint_as_float(u.w << 16)          * hv1.z;
                a3 += __uint_as_float(u.w & 0xffff0000u)  * hv1.w;
            }
            float acc = (a0 + a1) + (a2 + a3);
            #pragma unroll
            for (int off = 32; off; off >>= 1) acc += __shfl_xor(acc, off);
            sums[m] = acc;
        }

        // Gate math: lane 0 -> unit 2w, lane 1 -> unit 2w+1.
        const int cur = (t & 1) * 32;
        if (l < 2) {
            const int jj = 2 * w + l;          // local unit 0..7
            const int mb = l * 3;              // this lane's rows in sums[]
            const float h_r = sums[mb + 0] + bb[jj * 3 + 0];
            const float h_i = sums[mb + 1] + bb[jj * 3 + 1];
            const float h_n = sums[mb + 2] + bb[jj * 3 + 2];
            const float i_r = gxs[cur + jj * 3 + 0];
            const float i_i = gxs[cur + jj * 3 + 1];
            const float i_n = gxs[cur + jj * 3 + 2];
            const float rg = 1.f / (1.f + expf(-(i_r + h_r)));
            const float ig = 1.f / (1.f + expf(-(i_i + h_i)));
            const float ng = tanhf(i_n + rg * h_n);
            const int J = 8 * b + jj;
            log_h[(size_t)t * H_DIM + J] = ng + ig * (hs[J] - ng);
        }
        __threadfence();
        grid.sync();

        // Reload full h_t (8 KB) from global; write prefetched gx to LDS.
        {
            float4* hd = (float4*)hs;
            const float4* srch = (const float4*)(log_h + (size_t)t * H_DIM);
            hd[tid]       = srch[tid];
            hd[tid + 256] = srch[tid + 256];
        }
        if (pf) gxs[(~t & 1) * 32 + tid] = gpre;
        __syncthreads();
    }
}

// ---------------------------------------------------------------------------
// Fallback per-step kernel (round-1 path).
// ---------------------------------------------------------------------------
__global__ __launch_bounds__(192) void gru_step(
    const float* __restrict__ Whh, const float* __restrict__ bhh,
    const float* __restrict__ gx_t,
    const float* __restrict__ Wih, const float* __restrict__ bih,
    const float* __restrict__ X, int t,
    const float* __restrict__ h_prev, float* __restrict__ h_out)
{
    __shared__ __align__(16) float hsl[H_DIM];
    __shared__ float red[3], gred[3];
    const int tid = threadIdx.x;
    for (int i = tid; i < H_DIM; i += 192) hsl[i] = h_prev[i];
    __syncthreads();

    const int w = tid >> 6, lane = tid & 63;
    const int j = blockIdx.x;
    const int row = j + w * H_DIM;

    const float4* Wr = (const float4*)(Whh + (size_t)row * H_DIM);
    const float4* h4 = (const float4*)hsl;
    float acc = 0.f;
    #pragma unroll
    for (int k = 0; k < H_DIM / 256; ++k) {
        const float4 wv = Wr[lane + 64 * k];
        const float4 hv = h4[lane + 64 * k];
        acc += wv.x * hv.x + wv.y * hv.y + wv.z * hv.z + wv.w * hv.w;
    }
    float gacc = 0.f;
    if (gx_t == nullptr) {
        const float* Wi = Wih + (size_t)row * D_IN;
        #pragma unroll
        for (int k = 0; k < D_IN / 64; ++k) {
            const int d = lane + 64 * k;
            gacc += Wi[d] * X[(size_t)d * T_SEQ + t];
        }
    }
    #pragma unroll
    for (int off = 32; off > 0; off >>= 1) {
        acc  += __shfl_xor(acc, off);
        gacc += __shfl_xor(gacc, off);
    }
    if (lane == 0) {
        red[w]  = acc + bhh[row];
        gred[w] = gacc + ((gx_t == nullptr) ? bih[row] : 0.f);
    }
    __syncthreads();
    if (tid == 0) {
        float i_r, i_i, i_n;
        if (gx_t) { i_r = gx_t[j]; i_i = gx_t[j + H_DIM]; i_n = gx_t[j + 2 * H_DIM]; }
        else      { i_r = gred[0]; i_i = gred[1]; i_n = gred[2]; }
        const float h_r = red[0], h_i = red[1], h_n = red[2];
        const float rg = 1.f / (1.f + expf(-(i_r + h_r)));
        const float ig = 1.f / (1.f + expf(-(i_i + h_i)));
        const float ng = tanhf(i_n + rg * h_n);
        h_out[j] = ng + ig * (hsl[j] - ng);
    }
}

// ---------------------------------------------------------------------------
// Per-step loss + Pearson correlation.
// ---------------------------------------------------------------------------
__global__ __launch_bounds__(256) void loss_acc(
    const float* __restrict__ X, const float* __restrict__ yhat_all,
    float* __restrict__ log_loss, float* __restrict__ log_acc)
{
    const int t = blockIdx.x;
    const float* yh = yhat_all + (size_t)t * D_IN;
    const int tid = threadIdx.x;
    float s_y = 0, s_p = 0, s_yy = 0, s_pp = 0, s_yp = 0, s_d2 = 0;
    for (int d = tid; d < D_IN; d += 256) {
        const float y = X[(size_t)d * T_SEQ + (t + 1)];
        const float p = yh[d];
        const float df = y - p;
        s_y += y; s_p += p; s_yy += y * y; s_pp += p * p; s_yp += y * p; s_d2 += df * df;
    }
    #pragma unroll
    for (int off = 32; off > 0; off >>= 1) {
        s_y  += __shfl_xor(s_y, off);  s_p  += __shfl_xor(s_p, off);
        s_yy += __shfl_xor(s_yy, off); s_pp += __shfl_xor(s_pp, off);
        s_yp += __shfl_xor(s_yp, off); s_d2 += __shfl_xor(s_d2, off);
    }
    __shared__ float red[4][6];
    const int w = tid >> 6;
    if ((tid & 63) == 0) {
        red[w][0] = s_y; red[w][1] = s_p; red[w][2] = s_yy;
        red[w][3] = s_pp; red[w][4] = s_yp; red[w][5] = s_d2;
    }
    __syncthreads();
    if (tid == 0) {
        float a = 0, b = 0, cc = 0, dd = 0, e = 0, f = 0;
        for (int i = 0; i < 4; ++i) {
            a += red[i][0]; b += red[i][1]; cc += red[i][2];
            dd += red[i][3]; e += red[i][4]; f += red[i][5];
        }
        const float n = (float)D_IN;
        log_loss[t] = f / n;
        const float cov = e - a * b / n;
        const float vy  = cc - a * a / n;
        const float vp  = dd - b * b / n;
        log_acc[t] = cov / (sqrtf(vy) * sqrtf(vp));
    }
}

__global__ __launch_bounds__(256) void loss_sum(
    const float* __restrict__ log_loss, float* __restrict__ out)
{
    float s = 0;
    for (int i = threadIdx.x; i < S_SEQ; i += 256) s += log_loss[i];
    #pragma unroll
    for (int off = 32; off > 0; off >>= 1) s += __shfl_xor(s, off);
    __shared__ float red[4];
    if ((threadIdx.x & 63) == 0) red[threadIdx.x >> 6] = s;
    __syncthreads();
    if (threadIdx.x == 0) out[0] = red[0] + red[1] + red[2] + red[3];
}

// ---------------------------------------------------------------------------
extern "C" void kernel_launch(void* const* d_in, const int* in_sizes, int n_in,
                              void* d_out, int out_size, void* d_ws, size_t ws_size,
                              hipStream_t stream)
{
    const float* X   = (const float*)d_in[0];
    const float* h0  = (const float*)d_in[1];
    const float* Wih = (const float*)d_in[2];
    const float* bih = (const float*)d_in[3];
    const float* Whh = (const float*)d_in[4];
    const float* bhh = (const float*)d_in[5];
    const float* Who = (const float*)d_in[6];
    const float* bho = (const float*)d_in[7];

    float* out       = (float*)d_out;
    float* loss_out  = out;                               // [1]
    float* log_loss  = out + 1;                           // [4095]
    float* log_acc   = out + 1 + S_SEQ;                   // [4095]
    float* log_h     = out + 1 + 2 * S_SEQ;               // [4095*2048]
    float* log_yhat  = log_h + (size_t)S_SEQ * H_DIM;     // [4095*1024]

    const size_t wbf_bytes = (size_t)256 * 24 * 2048 * sizeof(unsigned short); // 24 MB
    const size_t gx_bytes  = (size_t)S_SEQ * H3 * sizeof(float);               // ~96 MB

    const bool full = (ws_size >= wbf_bytes + gx_bytes);
    unsigned short* wbf = full ? (unsigned short*)d_ws : nullptr;
    float* gx = full ? (float*)((char*)d_ws + wbf_bytes)
                     : ((ws_size >= gx_bytes) ? (float*)d_ws : nullptr);

    // Phase 1: gx_all = x_seq @ W_i2h^T + b_i2h  (parallel)
    if (gx) {
        dim3 g((S_SEQ + TS - 1) / TS, H3 / TS);
        gemm_bias<<<g, 256, 0, stream>>>(X, Wih, bih, gx, S_SEQ, H3, D_IN, T_SEQ, 1);
    }

    // Phase 2: sequential scan.
    bool coop_ok = false;
    if (full) {
        conv_whh<<<12288, 256, 0, stream>>>(Whh, wbf);
        hipFuncSetAttribute(reinterpret_cast<const void*>(gru_scan),
                            hipFuncAttributeMaxDynamicSharedMemorySize, SMEM_SZ);
        void* args[] = {(void*)&wbf, (void*)&bhh, (void*)&gx, (void*)&h0, (void*)&log_h};
        hipError_t ce = hipLaunchCooperativeKernel(
            reinterpret_cast<const void*>(gru_scan), dim3(256), dim3(256),
            args, (unsigned int)SMEM_SZ, stream);
        coop_ok = (ce == hipSuccess);
    }
    if (!coop_ok) {
        for (int t = 0; t < S_SEQ; ++t) {
            const float* hp = (t == 0) ? h0 : (log_h + (size_t)(t - 1) * H_DIM);
            gru_step<<<H_DIM, 192, 0, stream>>>(
                Whh, bhh, gx ? gx + (size_t)t * H3 : nullptr,
                Wih, bih, X, t, hp, log_h + (size_t)t * H_DIM);
        }
    }

    // Phase 3: log_yhat = log_h @ W_h2o^T + b_h2o
    {
        dim3 g((S_SEQ + TS - 1) / TS, D_IN / TS);
        gemm_bias<<<g, 256, 0, stream>>>(log_h, Who, bho, log_yhat, S_SEQ, D_IN, H_DIM, H_DIM, 0);
    }

    // Phase 4: per-step loss + Pearson corr, then total loss.
    loss_acc<<<S_SEQ, 256, 0, stream>>>(X, log_yhat, log_loss, log_acc);
    loss_sum<<<1, 256, 0, stream>>>(log_loss, loss_out);
}

// Round 3
// 90395.496 us; speedup vs baseline: 2.1940x; 2.1940x over previous
//
#include <hip/hip_runtime.h>
#include <math.h>

#define D_IN  1024
#define H_DIM 2048
#define H3    6144
#define T_SEQ 4096
#define S_SEQ 4095

// ---------------------------------------------------------------------------
// Tiled fp32 GEMM: C[M,N] = op(A)[M,K] @ B[N,K]^T + bias[N]
//   Atrans=1: A(m,k) = A[k*lda + m]   (gx: A = X, lda = T)
//   Atrans=0: A(m,k) = A[m*lda + k]   (yhat: A = log_h, lda = H)
// ---------------------------------------------------------------------------
#define TS 64
#define KS 16
#define LSTR 68

__global__ __launch_bounds__(256) void gemm_bias(
    const float* __restrict__ A, const float* __restrict__ B,
    const float* __restrict__ bias, float* __restrict__ C,
    int M, int N, int K, int lda, int Atrans)
{
    __shared__ __align__(16) float As[KS * LSTR];
    __shared__ __align__(16) float Bs[KS * LSTR];
    const int tid = threadIdx.x;
    const int m0 = blockIdx.x * TS;
    const int n0 = blockIdx.y * TS;
    const int tx = tid & 15, ty = tid >> 4;
    float c[4][4] = {};

    for (int k0 = 0; k0 < K; k0 += KS) {
        if (Atrans) {
            const int ml = tid & 63;
            const int kb = tid >> 6;
            #pragma unroll
            for (int kk = 0; kk < KS; kk += 4) {
                const int m = m0 + ml;
                As[(kk + kb) * LSTR + ml] =
                    (m < M) ? A[(size_t)(k0 + kk + kb) * lda + m] : 0.f;
            }
        } else {
            const int kl = tid & 15;
            const int mb = tid >> 4;
            #pragma unroll
            for (int ml = 0; ml < TS; ml += 16) {
                const int m = m0 + ml + mb;
                As[kl * LSTR + ml + mb] =
                    (m < M) ? A[(size_t)m * lda + (k0 + kl)] : 0.f;
            }
        }
        {
            const int kl = tid & 15;
            const int nb = tid >> 4;
            #pragma unroll
            for (int nl = 0; nl < TS; nl += 16) {
                Bs[kl * LSTR + nl + nb] = B[(size_t)(n0 + nl + nb) * K + (k0 + kl)];
            }
        }
        __syncthreads();
        #pragma unroll
        for (int kk = 0; kk < KS; ++kk) {
            const float4 a = *(const float4*)&As[kk * LSTR + tx * 4];
            const float4 b = *(const float4*)&Bs[kk * LSTR + ty * 4];
            c[0][0] += a.x * b.x; c[0][1] += a.x * b.y; c[0][2] += a.x * b.z; c[0][3] += a.x * b.w;
            c[1][0] += a.y * b.x; c[1][1] += a.y * b.y; c[1][2] += a.y * b.z; c[1][3] += a.y * b.w;
            c[2][0] += a.z * b.x; c[2][1] += a.z * b.y; c[2][2] += a.z * b.z; c[2][3] += a.z * b.w;
            c[3][0] += a.w * b.x; c[3][1] += a.w * b.y; c[3][2] += a.w * b.z; c[3][3] += a.w * b.w;
        }
        __syncthreads();
    }
    #pragma unroll
    for (int i = 0; i < 4; ++i) {
        const int m = m0 + tx * 4 + i;
        if (m < M) {
            #pragma unroll
            for (int j = 0; j < 4; ++j) {
                const int n = n0 + ty * 4 + j;
                C[(size_t)m * N + n] = c[i][j] + bias[n];
            }
        }
    }
}

// ---------------------------------------------------------------------------
// Convert W_h2h (fp32, [6144,2048] gate-major) to bf16, re-laid-out so that
// block b's 24 rows (units 8b..8b+7, r = jj*3+g -> global row 8b+jj+g*2048)
// are contiguous: wbf[((b*24 + r)*2048) + k].
// ---------------------------------------------------------------------------
__device__ inline unsigned short f2bf(float f) {
    union { float f; unsigned u; } a; a.f = f;
    unsigned u = a.u;
    u += 0x7fffu + ((u >> 16) & 1u);   // round-to-nearest-even
    return (unsigned short)(u >> 16);
}

__global__ __launch_bounds__(256) void conv_whh(
    const float* __restrict__ Whh, unsigned short* __restrict__ wbf)
{
    const int g = blockIdx.x * 256 + threadIdx.x;
    const size_t base = (size_t)g * 4;              // 4 elems per thread
    const int b   = (int)(base / 49152);            // 24*2048
    const int rem = (int)(base % 49152);
    const int r   = rem / 2048;
    const int k   = rem % 2048;
    const size_t srow = ((size_t)(8 * b + r / 3 + (r % 3) * H_DIM)) * H_DIM + k;
    const float4 v = *(const float4*)(Whh + srow);
    ushort4 o;
    o.x = f2bf(v.x); o.y = f2bf(v.y); o.z = f2bf(v.z); o.w = f2bf(v.w);
    *(ushort4*)(wbf + base) = o;
}

// ---------------------------------------------------------------------------
// Persistent cooperative scan with hand-rolled hierarchical barrier.
// 256 blocks x 256 threads, 1 block/CU. Block b owns units 8b..8b+7.
// h broadcast: agent-scope (MALL) atomic stores/loads on log_h row t.
// Barrier: monotonic 8-leaf + root + flag, all agent-scope atomics in d_ws.
// ---------------------------------------------------------------------------
#define SMEM_SZ (24 * 2048 * 2 + 2048 * 4 + 96 * 4)

__global__ __launch_bounds__(256, 1) void gru_scan(
    const unsigned short* __restrict__ wbf, const float* __restrict__ bhh,
    const float* __restrict__ gx, const float* __restrict__ h0,
    float* __restrict__ log_h, unsigned* __restrict__ bar)
{
    extern __shared__ char smem[];
    unsigned short* wlds = (unsigned short*)smem;            // 24*2048 bf16
    float* hs  = (float*)(smem + 24 * 2048 * 2);             // 2048 fp32
    float* gxs = (float*)(smem + 24 * 2048 * 2 + 2048 * 4);  // 2 x 32
    float* bb  = gxs + 64;                                   // 24

    const int tid = threadIdx.x;
    const int b = blockIdx.x;
    const int w = tid >> 6, l = tid & 63;

    unsigned* leaf = bar + (b & 7) * 32;    // 8 leaves, 128B apart
    unsigned* root = bar + 8 * 32;
    unsigned* flag = bar + 9 * 32;

    // Stage this block's weight slice into LDS (96 KB, coalesced 16B/lane).
    {
        const uint4* src = (const uint4*)(wbf + (size_t)b * 24 * 2048);
        uint4* dst = (uint4*)wlds;
        #pragma unroll
        for (int i = 0; i < 24; ++i) dst[tid + 256 * i] = src[tid + 256 * i];
    }
    for (int i = tid; i < H_DIM; i += 256) hs[i] = h0[i];
    if (tid < 24) {
        const int n = 8 * b + tid / 3 + (tid % 3) * H_DIM;
        bb[tid]  = bhh[n];
        gxs[tid] = gx[n];              // step-0 input gates (includes b_i2h)
    }
    __syncthreads();

    const int rbase = w * 6;
    for (int t = 0; t < S_SEQ; ++t) {
        // Prefetch next step's 24 gx values (consumed after next barrier).
        float gpre = 0.f;
        const bool pf = (tid < 24) && (t + 1 < S_SEQ);
        if (pf) gpre = gx[(size_t)(t + 1) * H3 + 8 * b + tid / 3 + (tid % 3) * H_DIM];

        // h chunk into registers: lane l covers k in [i*512 + l*8, +8).
        float4 hreg[8];
        const float4* hs4 = (const float4*)hs;
        #pragma unroll
        for (int i = 0; i < 4; ++i) {
            hreg[i * 2 + 0] = hs4[i * 128 + l * 2 + 0];
            hreg[i * 2 + 1] = hs4[i * 128 + l * 2 + 1];
        }

        // 6 row dots (bf16 weights, fp32 accumulate), full-wave butterfly.
        float sums[6];
        #pragma unroll
        for (int m = 0; m < 6; ++m) {
            const int r = rbase + m;
            const uint4* wrow = (const uint4*)wlds + r * 256;
            float a0 = 0.f, a1 = 0.f, a2 = 0.f, a3 = 0.f;
            #pragma unroll
            for (int i = 0; i < 4; ++i) {
                const uint4 u = wrow[i * 64 + l];
                const float4 hv0 = hreg[i * 2 + 0], hv1 = hreg[i * 2 + 1];
                a0 += __uint_as_float(u.x << 16)          * hv0.x;
                a1 += __uint_as_float(u.x & 0xffff0000u)  * hv0.y;
                a2 += __uint_as_float(u.y << 16)          * hv0.z;
                a3 += __uint_as_float(u.y & 0xffff0000u)  * hv0.w;
                a0 += __uint_as_float(u.z << 16)          * hv1.x;
                a1 += __uint_as_float(u.z & 0xffff0000u)  * hv1.y;
                a2 += __uint_as_float(u.w << 16)          * hv1.z;
                a3 += __uint_as_float(u.w & 0xffff0000u)  * hv1.w;
            }
            float acc = (a0 + a1) + (a2 + a3);
            #pragma unroll
            for (int off = 32; off; off >>= 1) acc += __shfl_xor(acc, off);
            sums[m] = acc;
        }

        // Gate math: lane 0 -> unit 2w, lane 1 -> unit 2w+1.
        const int cur = (t & 1) * 32;
        if (l < 2) {
            const int jj = 2 * w + l;          // local unit 0..7
            const int mb = l * 3;
            const float h_r = sums[mb + 0] + bb[jj * 3 + 0];
            const float h_i = sums[mb + 1] + bb[jj * 3 + 1];
            const float h_n = sums[mb + 2] + bb[jj * 3 + 2];
            const float i_r = gxs[cur + jj * 3 + 0];
            const float i_i = gxs[cur + jj * 3 + 1];
            const float i_n = gxs[cur + jj * 3 + 2];
            const float rg = 1.f / (1.f + expf(-(i_r + h_r)));
            const float ig = 1.f / (1.f + expf(-(i_i + h_i)));
            const float ng = tanhf(i_n + rg * h_n);
            const int J = 8 * b + jj;
            // Write-through to MALL (device coherence point).
            __hip_atomic_store(&log_h[(size_t)t * H_DIM + J],
                               ng + ig * (hs[J] - ng),
                               __ATOMIC_RELAXED, __HIP_MEMORY_SCOPE_AGENT);
        }

        if (t == S_SEQ - 1) break;

        // ---- hierarchical device barrier (monotonic counters) ----
        __syncthreads();   // drains vmcnt(0): block's h stores are at MALL
        if (tid == 0) {
            const unsigned tgt = (unsigned)(t + 1);
            unsigned v = __hip_atomic_fetch_add(leaf, 1u, __ATOMIC_ACQ_REL,
                                                __HIP_MEMORY_SCOPE_AGENT);
            if (v == 32u * tgt - 1u) {
                unsigned r = __hip_atomic_fetch_add(root, 1u, __ATOMIC_ACQ_REL,
                                                    __HIP_MEMORY_SCOPE_AGENT);
                if (r == 8u * tgt - 1u)
                    __hip_atomic_store(flag, tgt, __ATOMIC_RELEASE,
                                       __HIP_MEMORY_SCOPE_AGENT);
            }
            while (__hip_atomic_load(flag, __ATOMIC_ACQUIRE,
                                     __HIP_MEMORY_SCOPE_AGENT) < tgt)
                __builtin_amdgcn_s_sleep(1);
        }
        __syncthreads();

        // Reload full h_t (8 KB) from MALL; write prefetched gx to LDS.
        {
            const float* src = log_h + (size_t)t * H_DIM;
            #pragma unroll
            for (int i = 0; i < 8; ++i)
                hs[tid + 256 * i] = __hip_atomic_load(
                    &src[tid + 256 * i], __ATOMIC_RELAXED,
                    __HIP_MEMORY_SCOPE_AGENT);
        }
        if (pf) gxs[(~t & 1) * 32 + tid] = gpre;
        __syncthreads();
    }
}

// ---------------------------------------------------------------------------
// Fallback per-step kernel (round-1 path).
// ---------------------------------------------------------------------------
__global__ __launch_bounds__(192) void gru_step(
    const float* __restrict__ Whh, const float* __restrict__ bhh,
    const float* __restrict__ gx_t,
    const float* __restrict__ Wih, const float* __restrict__ bih,
    const float* __restrict__ X, int t,
    const float* __restrict__ h_prev, float* __restrict__ h_out)
{
    __shared__ __align__(16) float hsl[H_DIM];
    __shared__ float red[3], gred[3];
    const int tid = threadIdx.x;
    for (int i = tid; i < H_DIM; i += 192) hsl[i] = h_prev[i];
    __syncthreads();

    const int w = tid >> 6, lane = tid & 63;
    const int j = blockIdx.x;
    const int row = j + w * H_DIM;

    const float4* Wr = (const float4*)(Whh + (size_t)row * H_DIM);
    const float4* h4 = (const float4*)hsl;
    float acc = 0.f;
    #pragma unroll
    for (int k = 0; k < H_DIM / 256; ++k) {
        const float4 wv = Wr[lane + 64 * k];
        const float4 hv = h4[lane + 64 * k];
        acc += wv.x * hv.x + wv.y * hv.y + wv.z * hv.z + wv.w * hv.w;
    }
    float gacc = 0.f;
    if (gx_t == nullptr) {
        const float* Wi = Wih + (size_t)row * D_IN;
        #pragma unroll
        for (int k = 0; k < D_IN / 64; ++k) {
            const int d = lane + 64 * k;
            gacc += Wi[d] * X[(size_t)d * T_SEQ + t];
        }
    }
    #pragma unroll
    for (int off = 32; off > 0; off >>= 1) {
        acc  += __shfl_xor(acc, off);
        gacc += __shfl_xor(gacc, off);
    }
    if (lane == 0) {
        red[w]  = acc + bhh[row];
        gred[w] = gacc + ((gx_t == nullptr) ? bih[row] : 0.f);
    }
    __syncthreads();
    if (tid == 0) {
        float i_r, i_i, i_n;
        if (gx_t) { i_r = gx_t[j]; i_i = gx_t[j + H_DIM]; i_n = gx_t[j + 2 * H_DIM]; }
        else      { i_r = gred[0]; i_i = gred[1]; i_n = gred[2]; }
        const float h_r = red[0], h_i = red[1], h_n = red[2];
        const float rg = 1.f / (1.f + expf(-(i_r + h_r)));
        const float ig = 1.f / (1.f + expf(-(i_i + h_i)));
        const float ng = tanhf(i_n + rg * h_n);
        h_out[j] = ng + ig * (hsl[j] - ng);
    }
}

// ---------------------------------------------------------------------------
// Per-step loss + Pearson correlation.
// ---------------------------------------------------------------------------
__global__ __launch_bounds__(256) void loss_acc(
    const float* __restrict__ X, const float* __restrict__ yhat_all,
    float* __restrict__ log_loss, float* __restrict__ log_acc)
{
    const int t = blockIdx.x;
    const float* yh = yhat_all + (size_t)t * D_IN;
    const int tid = threadIdx.x;
    float s_y = 0, s_p = 0, s_yy = 0, s_pp = 0, s_yp = 0, s_d2 = 0;
    for (int d = tid; d < D_IN; d += 256) {
        const float y = X[(size_t)d * T_SEQ + (t + 1)];
        const float p = yh[d];
        const float df = y - p;
        s_y += y; s_p += p; s_yy += y * y; s_pp += p * p; s_yp += y * p; s_d2 += df * df;
    }
    #pragma unroll
    for (int off = 32; off > 0; off >>= 1) {
        s_y  += __shfl_xor(s_y, off);  s_p  += __shfl_xor(s_p, off);
        s_yy += __shfl_xor(s_yy, off); s_pp += __shfl_xor(s_pp, off);
        s_yp += __shfl_xor(s_yp, off); s_d2 += __shfl_xor(s_d2, off);
    }
    __shared__ float red[4][6];
    const int w = tid >> 6;
    if ((tid & 63) == 0) {
        red[w][0] = s_y; red[w][1] = s_p; red[w][2] = s_yy;
        red[w][3] = s_pp; red[w][4] = s_yp; red[w][5] = s_d2;
    }
    __syncthreads();
    if (tid == 0) {
        float a = 0, b = 0, cc = 0, dd = 0, e = 0, f = 0;
        for (int i = 0; i < 4; ++i) {
            a += red[i][0]; b += red[i][1]; cc += red[i][2];
            dd += red[i][3]; e += red[i][4]; f += red[i][5];
        }
        const float n = (float)D_IN;
        log_loss[t] = f / n;
        const float cov = e - a * b / n;
        const float vy  = cc - a * a / n;
        const float vp  = dd - b * b / n;
        log_acc[t] = cov / (sqrtf(vy) * sqrtf(vp));
    }
}

__global__ __launch_bounds__(256) void loss_sum(
    const float* __restrict__ log_loss, float* __restrict__ out)
{
    float s = 0;
    for (int i = threadIdx.x; i < S_SEQ; i += 256) s += log_loss[i];
    #pragma unroll
    for (int off = 32; off > 0; off >>= 1) s += __shfl_xor(s, off);
    __shared__ float red[4];
    if ((threadIdx.x & 63) == 0) red[threadIdx.x >> 6] = s;
    __syncthreads();
    if (threadIdx.x == 0) out[0] = red[0] + red[1] + red[2] + red[3];
}

// ---------------------------------------------------------------------------
extern "C" void kernel_launch(void* const* d_in, const int* in_sizes, int n_in,
                              void* d_out, int out_size, void* d_ws, size_t ws_size,
                              hipStream_t stream)
{
    const float* X   = (const float*)d_in[0];
    const float* h0  = (const float*)d_in[1];
    const float* Wih = (const float*)d_in[2];
    const float* bih = (const float*)d_in[3];
    const float* Whh = (const float*)d_in[4];
    const float* bhh = (const float*)d_in[5];
    const float* Who = (const float*)d_in[6];
    const float* bho = (const float*)d_in[7];

    float* out       = (float*)d_out;
    float* loss_out  = out;                               // [1]
    float* log_loss  = out + 1;                           // [4095]
    float* log_acc   = out + 1 + S_SEQ;                   // [4095]
    float* log_h     = out + 1 + 2 * S_SEQ;               // [4095*2048]
    float* log_yhat  = log_h + (size_t)S_SEQ * H_DIM;     // [4095*1024]

    const size_t wbf_bytes = (size_t)256 * 24 * 2048 * sizeof(unsigned short); // 24 MB
    const size_t gx_bytes  = (size_t)S_SEQ * H3 * sizeof(float);               // ~96 MB
    const size_t bar_bytes = 4096;

    const bool full = (ws_size >= wbf_bytes + gx_bytes + bar_bytes);
    unsigned short* wbf = full ? (unsigned short*)d_ws : nullptr;
    float* gx = full ? (float*)((char*)d_ws + wbf_bytes)
                     : ((ws_size >= gx_bytes) ? (float*)d_ws : nullptr);
    unsigned* bar = full ? (unsigned*)((char*)d_ws + wbf_bytes + gx_bytes) : nullptr;

    // Phase 1: gx_all = x_seq @ W_i2h^T + b_i2h  (parallel)
    if (gx) {
        dim3 g((S_SEQ + TS - 1) / TS, H3 / TS);
        gemm_bias<<<g, 256, 0, stream>>>(X, Wih, bih, gx, S_SEQ, H3, D_IN, T_SEQ, 1);
    }

    // Phase 2: sequential scan.
    bool coop_ok = false;
    if (full) {
        hipMemsetAsync(bar, 0, bar_bytes, stream);        // deterministic barrier state
        conv_whh<<<12288, 256, 0, stream>>>(Whh, wbf);
        hipFuncSetAttribute(reinterpret_cast<const void*>(gru_scan),
                            hipFuncAttributeMaxDynamicSharedMemorySize, SMEM_SZ);
        void* args[] = {(void*)&wbf, (void*)&bhh, (void*)&gx, (void*)&h0,
                        (void*)&log_h, (void*)&bar};
        hipError_t ce = hipLaunchCooperativeKernel(
            reinterpret_cast<const void*>(gru_scan), dim3(256), dim3(256),
            args, (unsigned int)SMEM_SZ, stream);
        coop_ok = (ce == hipSuccess);
    }
    if (!coop_ok) {
        for (int t = 0; t < S_SEQ; ++t) {
            const float* hp = (t == 0) ? h0 : (log_h + (size_t)(t - 1) * H_DIM);
            gru_step<<<H_DIM, 192, 0, stream>>>(
                Whh, bhh, gx ? gx + (size_t)t * H3 : nullptr,
                Wih, bih, X, t, hp, log_h + (size_t)t * H_DIM);
        }
    }

    // Phase 3: log_yhat = log_h @ W_h2o^T + b_h2o
    {
        dim3 g((S_SEQ + TS - 1) / TS, D_IN / TS);
        gemm_bias<<<g, 256, 0, stream>>>(log_h, Who, bho, log_yhat, S_SEQ, D_IN, H_DIM, H_DIM, 0);
    }

    // Phase 4: per-step loss + Pearson corr, then total loss.
    loss_acc<<<S_SEQ, 256, 0, stream>>>(X, log_yhat, log_loss, log_acc);
    loss_sum<<<1, 256, 0, stream>>>(log_loss, loss_out);
}

// Round 4
// 25728.366 us; speedup vs baseline: 7.7086x; 3.5135x over previous
//
#include <hip/hip_runtime.h>
#include <math.h>

#define D_IN  1024
#define H_DIM 2048
#define H3    6144
#define T_SEQ 4096
#define S_SEQ 4095

// ---------------------------------------------------------------------------
// Tiled fp32 GEMM: C[M,N] = op(A)[M,K] @ B[N,K]^T + bias[N]
//   Atrans=1: A(m,k) = A[k*lda + m]   (gx: A = X, lda = T)
//   Atrans=0: A(m,k) = A[m*lda + k]   (yhat: A = log_h, lda = H)
// ---------------------------------------------------------------------------
#define TS 64
#define KS 16
#define LSTR 68

__global__ __launch_bounds__(256) void gemm_bias(
    const float* __restrict__ A, const float* __restrict__ B,
    const float* __restrict__ bias, float* __restrict__ C,
    int M, int N, int K, int lda, int Atrans)
{
    __shared__ __align__(16) float As[KS * LSTR];
    __shared__ __align__(16) float Bs[KS * LSTR];
    const int tid = threadIdx.x;
    const int m0 = blockIdx.x * TS;
    const int n0 = blockIdx.y * TS;
    const int tx = tid & 15, ty = tid >> 4;
    float c[4][4] = {};

    for (int k0 = 0; k0 < K; k0 += KS) {
        if (Atrans) {
            const int ml = tid & 63;
            const int kb = tid >> 6;
            #pragma unroll
            for (int kk = 0; kk < KS; kk += 4) {
                const int m = m0 + ml;
                As[(kk + kb) * LSTR + ml] =
                    (m < M) ? A[(size_t)(k0 + kk + kb) * lda + m] : 0.f;
            }
        } else {
            const int kl = tid & 15;
            const int mb = tid >> 4;
            #pragma unroll
            for (int ml = 0; ml < TS; ml += 16) {
                const int m = m0 + ml + mb;
                As[kl * LSTR + ml + mb] =
                    (m < M) ? A[(size_t)m * lda + (k0 + kl)] : 0.f;
            }
        }
        {
            const int kl = tid & 15;
            const int nb = tid >> 4;
            #pragma unroll
            for (int nl = 0; nl < TS; nl += 16) {
                Bs[kl * LSTR + nl + nb] = B[(size_t)(n0 + nl + nb) * K + (k0 + kl)];
            }
        }
        __syncthreads();
        #pragma unroll
        for (int kk = 0; kk < KS; ++kk) {
            const float4 a = *(const float4*)&As[kk * LSTR + tx * 4];
            const float4 b = *(const float4*)&Bs[kk * LSTR + ty * 4];
            c[0][0] += a.x * b.x; c[0][1] += a.x * b.y; c[0][2] += a.x * b.z; c[0][3] += a.x * b.w;
            c[1][0] += a.y * b.x; c[1][1] += a.y * b.y; c[1][2] += a.y * b.z; c[1][3] += a.y * b.w;
            c[2][0] += a.z * b.x; c[2][1] += a.z * b.y; c[2][2] += a.z * b.z; c[2][3] += a.z * b.w;
            c[3][0] += a.w * b.x; c[3][1] += a.w * b.y; c[3][2] += a.w * b.z; c[3][3] += a.w * b.w;
        }
        __syncthreads();
    }
    #pragma unroll
    for (int i = 0; i < 4; ++i) {
        const int m = m0 + tx * 4 + i;
        if (m < M) {
            #pragma unroll
            for (int j = 0; j < 4; ++j) {
                const int n = n0 + ty * 4 + j;
                C[(size_t)m * N + n] = c[i][j] + bias[n];
            }
        }
    }
}

// ---------------------------------------------------------------------------
// Convert W_h2h (fp32, [6144,2048] gate-major) to bf16, re-laid-out so that
// block b's 24 rows (units 8b..8b+7, r = jj*3+g -> global row 8b+jj+g*2048)
// are contiguous: wbf[((b*24 + r)*2048) + k].
// ---------------------------------------------------------------------------
__device__ inline unsigned short f2bf(float f) {
    union { float f; unsigned u; } a; a.f = f;
    unsigned u = a.u;
    u += 0x7fffu + ((u >> 16) & 1u);   // round-to-nearest-even
    return (unsigned short)(u >> 16);
}

__global__ __launch_bounds__(256) void conv_whh(
    const float* __restrict__ Whh, unsigned short* __restrict__ wbf)
{
    const int g = blockIdx.x * 256 + threadIdx.x;
    const size_t base = (size_t)g * 4;              // 4 elems per thread
    const int b   = (int)(base / 49152);            // 24*2048
    const int rem = (int)(base % 49152);
    const int r   = rem / 2048;
    const int k   = rem % 2048;
    const size_t srow = ((size_t)(8 * b + r / 3 + (r % 3) * H_DIM)) * H_DIM + k;
    const float4 v = *(const float4*)(Whh + srow);
    ushort4 o;
    o.x = f2bf(v.x); o.y = f2bf(v.y); o.z = f2bf(v.z); o.w = f2bf(v.w);
    *(ushort4*)(wbf + base) = o;
}

// ---------------------------------------------------------------------------
// Persistent cooperative scan. 256 blocks x 256 threads, 1 block/CU.
// Block b owns units 8b..8b+7 (3 bf16 gate rows each, resident in LDS).
// Cross-block traffic is MALL-direct (agent-scope RELAXED = sc0 sc1,
// bypassing the non-coherent per-XCD L2s) with ZERO cache-maintenance ops:
//   arrive:  __syncthreads (drains vmcnt -> h stores ack'd at MALL)
//            tid0 stores slot[b] = t+1            (relaxed, MALL)
//   gather:  block0's 256 threads poll the 256 slots in parallel (relaxed)
//   release: block0 tid0 stores flag = t+1         (relaxed, MALL)
//   wait:    other blocks' tid0 polls flag          (relaxed, MALL)
// Monotonic values; state zeroed on-stream each call -> graph-replay safe.
// ---------------------------------------------------------------------------
#define SMEM_SZ (24 * 2048 * 2 + 2048 * 4 + 96 * 4)

__global__ __launch_bounds__(256, 1) void gru_scan(
    const unsigned short* __restrict__ wbf, const float* __restrict__ bhh,
    const float* __restrict__ gx, const float* __restrict__ h0,
    float* __restrict__ log_h, unsigned* __restrict__ bar)
{
    extern __shared__ char smem[];
    unsigned short* wlds = (unsigned short*)smem;            // 24*2048 bf16
    float* hs  = (float*)(smem + 24 * 2048 * 2);             // 2048 fp32
    float* gxs = (float*)(smem + 24 * 2048 * 2 + 2048 * 4);  // 2 x 32
    float* bb  = gxs + 64;                                   // 24

    const int tid = threadIdx.x;
    const int b = blockIdx.x;
    const int w = tid >> 6, l = tid & 63;

    unsigned* slot = bar + b * 32;          // one 128B line per block
    unsigned* flag = bar + 256 * 32;

    // Stage this block's weight slice into LDS (96 KB, coalesced 16B/lane).
    {
        const uint4* src = (const uint4*)(wbf + (size_t)b * 24 * 2048);
        uint4* dst = (uint4*)wlds;
        #pragma unroll
        for (int i = 0; i < 24; ++i) dst[tid + 256 * i] = src[tid + 256 * i];
    }
    for (int i = tid; i < H_DIM; i += 256) hs[i] = h0[i];
    if (tid < 24) {
        const int n = 8 * b + tid / 3 + (tid % 3) * H_DIM;
        bb[tid]  = bhh[n];
        gxs[tid] = gx[n];              // step-0 input gates (includes b_i2h)
    }
    __syncthreads();

    const int rbase = w * 6;
    for (int t = 0; t < S_SEQ; ++t) {
        // Prefetch next step's 24 gx values (consumed after next barrier).
        float gpre = 0.f;
        const bool pf = (tid < 24) && (t + 1 < S_SEQ);
        if (pf) gpre = gx[(size_t)(t + 1) * H3 + 8 * b + tid / 3 + (tid % 3) * H_DIM];

        // h chunk into registers: lane l covers k in [i*512 + l*8, +8).
        float4 hreg[8];
        const float4* hs4 = (const float4*)hs;
        #pragma unroll
        for (int i = 0; i < 4; ++i) {
            hreg[i * 2 + 0] = hs4[i * 128 + l * 2 + 0];
            hreg[i * 2 + 1] = hs4[i * 128 + l * 2 + 1];
        }

        // 6 row dots (bf16 weights, fp32 accumulate), full-wave butterfly.
        float sums[6];
        #pragma unroll
        for (int m = 0; m < 6; ++m) {
            const int r = rbase + m;
            const uint4* wrow = (const uint4*)wlds + r * 256;
            float a0 = 0.f, a1 = 0.f, a2 = 0.f, a3 = 0.f;
            #pragma unroll
            for (int i = 0; i < 4; ++i) {
                const uint4 u = wrow[i * 64 + l];
                const float4 hv0 = hreg[i * 2 + 0], hv1 = hreg[i * 2 + 1];
                a0 += __uint_as_float(u.x << 16)          * hv0.x;
                a1 += __uint_as_float(u.x & 0xffff0000u)  * hv0.y;
                a2 += __uint_as_float(u.y << 16)          * hv0.z;
                a3 += __uint_as_float(u.y & 0xffff0000u)  * hv0.w;
                a0 += __uint_as_float(u.z << 16)          * hv1.x;
                a1 += __uint_as_float(u.z & 0xffff0000u)  * hv1.y;
                a2 += __uint_as_float(u.w << 16)          * hv1.z;
                a3 += __uint_as_float(u.w & 0xffff0000u)  * hv1.w;
            }
            float acc = (a0 + a1) + (a2 + a3);
            #pragma unroll
            for (int off = 32; off; off >>= 1) acc += __shfl_xor(acc, off);
            sums[m] = acc;
        }

        // Gate math: lane 0 -> unit 2w, lane 1 -> unit 2w+1.
        const int cur = (t & 1) * 32;
        if (l < 2) {
            const int jj = 2 * w + l;          // local unit 0..7
            const int mb = l * 3;
            const float h_r = sums[mb + 0] + bb[jj * 3 + 0];
            const float h_i = sums[mb + 1] + bb[jj * 3 + 1];
            const float h_n = sums[mb + 2] + bb[jj * 3 + 2];
            const float i_r = gxs[cur + jj * 3 + 0];
            const float i_i = gxs[cur + jj * 3 + 1];
            const float i_n = gxs[cur + jj * 3 + 2];
            const float rg = 1.f / (1.f + expf(-(i_r + h_r)));
            const float ig = 1.f / (1.f + expf(-(i_i + h_i)));
            const float ng = tanhf(i_n + rg * h_n);
            const int J = 8 * b + jj;
            // Write-through to MALL (device coherence point).
            __hip_atomic_store(&log_h[(size_t)t * H_DIM + J],
                               ng + ig * (hs[J] - ng),
                               __ATOMIC_RELAXED, __HIP_MEMORY_SCOPE_AGENT);
        }

        if (t == S_SEQ - 1) break;

        // ---- MALL-direct device barrier (no cache-maintenance ops) ----
        const unsigned tgt = (unsigned)(t + 1);
        __syncthreads();   // s_waitcnt vmcnt(0): h stores ack'd at MALL
        if (tid == 0)
            __hip_atomic_store(slot, tgt, __ATOMIC_RELAXED,
                               __HIP_MEMORY_SCOPE_AGENT);
        if (b == 0) {
            unsigned* s = bar + tid * 32;      // thread tid watches block tid
            while (__hip_atomic_load(s, __ATOMIC_RELAXED,
                                     __HIP_MEMORY_SCOPE_AGENT) < tgt) {}
            __syncthreads();                   // all 256 slots arrived
            if (tid == 0)
                __hip_atomic_store(flag, tgt, __ATOMIC_RELAXED,
                                   __HIP_MEMORY_SCOPE_AGENT);
        } else {
            if (tid == 0) {
                while (__hip_atomic_load(flag, __ATOMIC_RELAXED,
                                         __HIP_MEMORY_SCOPE_AGENT) < tgt) {}
            }
            __syncthreads();
        }

        // Reload full h_t (8 KB) from MALL; write prefetched gx to LDS.
        {
            const float* src = log_h + (size_t)t * H_DIM;
            #pragma unroll
            for (int i = 0; i < 8; ++i)
                hs[tid + 256 * i] = __hip_atomic_load(
                    &src[tid + 256 * i], __ATOMIC_RELAXED,
                    __HIP_MEMORY_SCOPE_AGENT);
        }
        if (pf) gxs[(~t & 1) * 32 + tid] = gpre;
        __syncthreads();
    }
}

// ---------------------------------------------------------------------------
// Fallback per-step kernel (round-1 path).
// ---------------------------------------------------------------------------
__global__ __launch_bounds__(192) void gru_step(
    const float* __restrict__ Whh, const float* __restrict__ bhh,
    const float* __restrict__ gx_t,
    const float* __restrict__ Wih, const float* __restrict__ bih,
    const float* __restrict__ X, int t,
    const float* __restrict__ h_prev, float* __restrict__ h_out)
{
    __shared__ __align__(16) float hsl[H_DIM];
    __shared__ float red[3], gred[3];
    const int tid = threadIdx.x;
    for (int i = tid; i < H_DIM; i += 192) hsl[i] = h_prev[i];
    __syncthreads();

    const int w = tid >> 6, lane = tid & 63;
    const int j = blockIdx.x;
    const int row = j + w * H_DIM;

    const float4* Wr = (const float4*)(Whh + (size_t)row * H_DIM);
    const float4* h4 = (const float4*)hsl;
    float acc = 0.f;
    #pragma unroll
    for (int k = 0; k < H_DIM / 256; ++k) {
        const float4 wv = Wr[lane + 64 * k];
        const float4 hv = h4[lane + 64 * k];
        acc += wv.x * hv.x + wv.y * hv.y + wv.z * hv.z + wv.w * hv.w;
    }
    float gacc = 0.f;
    if (gx_t == nullptr) {
        const float* Wi = Wih + (size_t)row * D_IN;
        #pragma unroll
        for (int k = 0; k < D_IN / 64; ++k) {
            const int d = lane + 64 * k;
            gacc += Wi[d] * X[(size_t)d * T_SEQ + t];
        }
    }
    #pragma unroll
    for (int off = 32; off > 0; off >>= 1) {
        acc  += __shfl_xor(acc, off);
        gacc += __shfl_xor(gacc, off);
    }
    if (lane == 0) {
        red[w]  = acc + bhh[row];
        gred[w] = gacc + ((gx_t == nullptr) ? bih[row] : 0.f);
    }
    __syncthreads();
    if (tid == 0) {
        float i_r, i_i, i_n;
        if (gx_t) { i_r = gx_t[j]; i_i = gx_t[j + H_DIM]; i_n = gx_t[j + 2 * H_DIM]; }
        else      { i_r = gred[0]; i_i = gred[1]; i_n = gred[2]; }
        const float h_r = red[0], h_i = red[1], h_n = red[2];
        const float rg = 1.f / (1.f + expf(-(i_r + h_r)));
        const float ig = 1.f / (1.f + expf(-(i_i + h_i)));
        const float ng = tanhf(i_n + rg * h_n);
        h_out[j] = ng + ig * (hsl[j] - ng);
    }
}

// ---------------------------------------------------------------------------
// Per-step loss + Pearson correlation.
// ---------------------------------------------------------------------------
__global__ __launch_bounds__(256) void loss_acc(
    const float* __restrict__ X, const float* __restrict__ yhat_all,
    float* __restrict__ log_loss, float* __restrict__ log_acc)
{
    const int t = blockIdx.x;
    const float* yh = yhat_all + (size_t)t * D_IN;
    const int tid = threadIdx.x;
    float s_y = 0, s_p = 0, s_yy = 0, s_pp = 0, s_yp = 0, s_d2 = 0;
    for (int d = tid; d < D_IN; d += 256) {
        const float y = X[(size_t)d * T_SEQ + (t + 1)];
        const float p = yh[d];
        const float df = y - p;
        s_y += y; s_p += p; s_yy += y * y; s_pp += p * p; s_yp += y * p; s_d2 += df * df;
    }
    #pragma unroll
    for (int off = 32; off > 0; off >>= 1) {
        s_y  += __shfl_xor(s_y, off);  s_p  += __shfl_xor(s_p, off);
        s_yy += __shfl_xor(s_yy, off); s_pp += __shfl_xor(s_pp, off);
        s_yp += __shfl_xor(s_yp, off); s_d2 += __shfl_xor(s_d2, off);
    }
    __shared__ float red[4][6];
    const int w = tid >> 6;
    if ((tid & 63) == 0) {
        red[w][0] = s_y; red[w][1] = s_p; red[w][2] = s_yy;
        red[w][3] = s_pp; red[w][4] = s_yp; red[w][5] = s_d2;
    }
    __syncthreads();
    if (tid == 0) {
        float a = 0, b = 0, cc = 0, dd = 0, e = 0, f = 0;
        for (int i = 0; i < 4; ++i) {
            a += red[i][0]; b += red[i][1]; cc += red[i][2];
            dd += red[i][3]; e += red[i][4]; f += red[i][5];
        }
        const float n = (float)D_IN;
        log_loss[t] = f / n;
        const float cov = e - a * b / n;
        const float vy  = cc - a * a / n;
        const float vp  = dd - b * b / n;
        log_acc[t] = cov / (sqrtf(vy) * sqrtf(vp));
    }
}

__global__ __launch_bounds__(256) void loss_sum(
    const float* __restrict__ log_loss, float* __restrict__ out)
{
    float s = 0;
    for (int i = threadIdx.x; i < S_SEQ; i += 256) s += log_loss[i];
    #pragma unroll
    for (int off = 32; off > 0; off >>= 1) s += __shfl_xor(s, off);
    __shared__ float red[4];
    if ((threadIdx.x & 63) == 0) red[threadIdx.x >> 6] = s;
    __syncthreads();
    if (threadIdx.x == 0) out[0] = red[0] + red[1] + red[2] + red[3];
}

// ---------------------------------------------------------------------------
extern "C" void kernel_launch(void* const* d_in, const int* in_sizes, int n_in,
                              void* d_out, int out_size, void* d_ws, size_t ws_size,
                              hipStream_t stream)
{
    const float* X   = (const float*)d_in[0];
    const float* h0  = (const float*)d_in[1];
    const float* Wih = (const float*)d_in[2];
    const float* bih = (const float*)d_in[3];
    const float* Whh = (const float*)d_in[4];
    const float* bhh = (const float*)d_in[5];
    const float* Who = (const float*)d_in[6];
    const float* bho = (const float*)d_in[7];

    float* out       = (float*)d_out;
    float* loss_out  = out;                               // [1]
    float* log_loss  = out + 1;                           // [4095]
    float* log_acc   = out + 1 + S_SEQ;                   // [4095]
    float* log_h     = out + 1 + 2 * S_SEQ;               // [4095*2048]
    float* log_yhat  = log_h + (size_t)S_SEQ * H_DIM;     // [4095*1024]

    const size_t wbf_bytes = (size_t)256 * 24 * 2048 * sizeof(unsigned short); // 24 MB
    const size_t gx_bytes  = (size_t)S_SEQ * H3 * sizeof(float);               // ~96 MB
    const size_t bar_bytes = (256 * 32 + 32) * sizeof(unsigned);               // ~33 KB

    const bool full = (ws_size >= wbf_bytes + gx_bytes + bar_bytes);
    unsigned short* wbf = full ? (unsigned short*)d_ws : nullptr;
    float* gx = full ? (float*)((char*)d_ws + wbf_bytes)
                     : ((ws_size >= gx_bytes) ? (float*)d_ws : nullptr);
    unsigned* bar = full ? (unsigned*)((char*)d_ws + wbf_bytes + gx_bytes) : nullptr;

    // Phase 1: gx_all = x_seq @ W_i2h^T + b_i2h  (parallel)
    if (gx) {
        dim3 g((S_SEQ + TS - 1) / TS, H3 / TS);
        gemm_bias<<<g, 256, 0, stream>>>(X, Wih, bih, gx, S_SEQ, H3, D_IN, T_SEQ, 1);
    }

    // Phase 2: sequential scan.
    bool coop_ok = false;
    if (full) {
        hipMemsetAsync(bar, 0, bar_bytes, stream);        // deterministic barrier state
        conv_whh<<<12288, 256, 0, stream>>>(Whh, wbf);
        hipFuncSetAttribute(reinterpret_cast<const void*>(gru_scan),
                            hipFuncAttributeMaxDynamicSharedMemorySize, SMEM_SZ);
        void* args[] = {(void*)&wbf, (void*)&bhh, (void*)&gx, (void*)&h0,
                        (void*)&log_h, (void*)&bar};
        hipError_t ce = hipLaunchCooperativeKernel(
            reinterpret_cast<const void*>(gru_scan), dim3(256), dim3(256),
            args, (unsigned int)SMEM_SZ, stream);
        coop_ok = (ce == hipSuccess);
    }
    if (!coop_ok) {
        for (int t = 0; t < S_SEQ; ++t) {
            const float* hp = (t == 0) ? h0 : (log_h + (size_t)(t - 1) * H_DIM);
            gru_step<<<H_DIM, 192, 0, stream>>>(
                Whh, bhh, gx ? gx + (size_t)t * H3 : nullptr,
                Wih, bih, X, t, hp, log_h + (size_t)t * H_DIM);
        }
    }

    // Phase 3: log_yhat = log_h @ W_h2o^T + b_h2o
    {
        dim3 g((S_SEQ + TS - 1) / TS, D_IN / TS);
        gemm_bias<<<g, 256, 0, stream>>>(log_h, Who, bho, log_yhat, S_SEQ, D_IN, H_DIM, H_DIM, 0);
    }

    // Phase 4: per-step loss + Pearson corr, then total loss.
    loss_acc<<<S_SEQ, 256, 0, stream>>>(X, log_yhat, log_loss, log_acc);
    loss_sum<<<1, 256, 0, stream>>>(log_loss, loss_out);
}

// Round 5
// 25591.141 us; speedup vs baseline: 7.7499x; 1.0054x over previous
//
#include <hip/hip_runtime.h>
#include <math.h>

#define D_IN  1024
#define H_DIM 2048
#define H3    6144
#define T_SEQ 4096
#define S_SEQ 4095

// ---------------------------------------------------------------------------
// Tiled fp32 GEMM: C[M,N] = op(A)[M,K] @ B[N,K]^T + bias[N]
//   Atrans=1: A(m,k) = A[k*lda + m]   (gx: A = X, lda = T)
//   Atrans=0: A(m,k) = A[m*lda + k]   (yhat: A = log_h, lda = H)
// permOut=1: output column n = g*2048+u is written to position
//   (u>>3)*24 + (u&7)*3 + g   (block-major gx layout for the scan)
// ---------------------------------------------------------------------------
#define TS 64
#define KS 16
#define LSTR 68

__global__ __launch_bounds__(256) void gemm_bias(
    const float* __restrict__ A, const float* __restrict__ B,
    const float* __restrict__ bias, float* __restrict__ C,
    int M, int N, int K, int lda, int Atrans, int permOut)
{
    __shared__ __align__(16) float As[KS * LSTR];
    __shared__ __align__(16) float Bs[KS * LSTR];
    const int tid = threadIdx.x;
    const int m0 = blockIdx.x * TS;
    const int n0 = blockIdx.y * TS;
    const int tx = tid & 15, ty = tid >> 4;
    float c[4][4] = {};

    for (int k0 = 0; k0 < K; k0 += KS) {
        if (Atrans) {
            const int ml = tid & 63;
            const int kb = tid >> 6;
            #pragma unroll
            for (int kk = 0; kk < KS; kk += 4) {
                const int m = m0 + ml;
                As[(kk + kb) * LSTR + ml] =
                    (m < M) ? A[(size_t)(k0 + kk + kb) * lda + m] : 0.f;
            }
        } else {
            const int kl = tid & 15;
            const int mb = tid >> 4;
            #pragma unroll
            for (int ml = 0; ml < TS; ml += 16) {
                const int m = m0 + ml + mb;
                As[kl * LSTR + ml + mb] =
                    (m < M) ? A[(size_t)m * lda + (k0 + kl)] : 0.f;
            }
        }
        {
            const int kl = tid & 15;
            const int nb = tid >> 4;
            #pragma unroll
            for (int nl = 0; nl < TS; nl += 16) {
                Bs[kl * LSTR + nl + nb] = B[(size_t)(n0 + nl + nb) * K + (k0 + kl)];
            }
        }
        __syncthreads();
        #pragma unroll
        for (int kk = 0; kk < KS; ++kk) {
            const float4 a = *(const float4*)&As[kk * LSTR + tx * 4];
            const float4 b = *(const float4*)&Bs[kk * LSTR + ty * 4];
            c[0][0] += a.x * b.x; c[0][1] += a.x * b.y; c[0][2] += a.x * b.z; c[0][3] += a.x * b.w;
            c[1][0] += a.y * b.x; c[1][1] += a.y * b.y; c[1][2] += a.y * b.z; c[1][3] += a.y * b.w;
            c[2][0] += a.z * b.x; c[2][1] += a.z * b.y; c[2][2] += a.z * b.z; c[2][3] += a.z * b.w;
            c[3][0] += a.w * b.x; c[3][1] += a.w * b.y; c[3][2] += a.w * b.z; c[3][3] += a.w * b.w;
        }
        __syncthreads();
    }
    #pragma unroll
    for (int i = 0; i < 4; ++i) {
        const int m = m0 + tx * 4 + i;
        if (m < M) {
            #pragma unroll
            for (int j = 0; j < 4; ++j) {
                const int n = n0 + ty * 4 + j;
                size_t cidx;
                if (permOut) {
                    const int g = n >> 11, u = n & 2047;
                    cidx = (size_t)m * N + ((u >> 3) * 24 + (u & 7) * 3 + g);
                } else {
                    cidx = (size_t)m * N + n;
                }
                C[cidx] = c[i][j] + bias[n];
            }
        }
    }
}

// ---------------------------------------------------------------------------
// Convert W_h2h (fp32, [6144,2048] gate-major) to bf16, re-laid-out so that
// block b's 24 rows (units 8b..8b+7, r = jj*3+g -> global row 8b+jj+g*2048)
// are contiguous: wbf[((b*24 + r)*2048) + k].
// ---------------------------------------------------------------------------
__device__ inline unsigned short f2bf(float f) {
    union { float f; unsigned u; } a; a.f = f;
    unsigned u = a.u;
    u += 0x7fffu + ((u >> 16) & 1u);   // round-to-nearest-even
    return (unsigned short)(u >> 16);
}

__global__ __launch_bounds__(256) void conv_whh(
    const float* __restrict__ Whh, unsigned short* __restrict__ wbf)
{
    const int g = blockIdx.x * 256 + threadIdx.x;
    const size_t base = (size_t)g * 4;              // 4 elems per thread
    const int b   = (int)(base / 49152);            // 24*2048
    const int rem = (int)(base % 49152);
    const int r   = rem / 2048;
    const int k   = rem % 2048;
    const size_t srow = ((size_t)(8 * b + r / 3 + (r % 3) * H_DIM)) * H_DIM + k;
    const float4 v = *(const float4*)(Whh + srow);
    ushort4 o;
    o.x = f2bf(v.x); o.y = f2bf(v.y); o.z = f2bf(v.z); o.w = f2bf(v.w);
    *(ushort4*)(wbf + base) = o;
}

// ---------------------------------------------------------------------------
// Persistent cooperative scan. 256 blocks x 256 threads, 1 block/CU.
// Block b owns units 8b..8b+7 (3 bf16 gate rows each, resident in LDS).
//
// Sync = data-carrying slot lines, MALL-direct (agent-relaxed sc0 sc1),
// parity double-buffered:
//   write:  lanes scatter 8 h values into own 64B slot (relaxed, MALL)
//           __syncthreads (drains every wave's vmcnt -> stores ack'd)
//           tid0 stores slot tag = t+1 (relaxed, MALL)
//   read:   thread tid polls slot (tid+b)&255's tag, then reads its 8
//           floats and writes them to LDS hs. One MALL round trip total.
// Parity safety: a block only overwrites parity-p slots after all blocks
// posted parity-(1-p) tags, which certifies all finished READING parity p.
// ---------------------------------------------------------------------------
#define SMEM_SZ (24 * 2048 * 2 + 2048 * 4 + 96 * 4)

__global__ __launch_bounds__(256, 1) void gru_scan(
    const unsigned short* __restrict__ wbf, const float* __restrict__ bhh,
    const float* __restrict__ gx, const float* __restrict__ h0,
    float* __restrict__ log_h, unsigned* __restrict__ bar)
{
    extern __shared__ char smem[];
    unsigned short* wlds = (unsigned short*)smem;            // 24*2048 bf16
    float* hs  = (float*)(smem + 24 * 2048 * 2);             // 2048 fp32
    float* gxs = (float*)(smem + 24 * 2048 * 2 + 2048 * 4);  // 2 x 32
    float* bb  = gxs + 64;                                   // 24

    const int tid = threadIdx.x;
    const int b = blockIdx.x;
    const int w = tid >> 6, l = tid & 63;

    // Stage this block's weight slice into LDS (96 KB, coalesced 16B/lane).
    {
        const uint4* src = (const uint4*)(wbf + (size_t)b * 24 * 2048);
        uint4* dst = (uint4*)wlds;
        #pragma unroll
        for (int i = 0; i < 24; ++i) dst[tid + 256 * i] = src[tid + 256 * i];
    }
    for (int i = tid; i < H_DIM; i += 256) hs[i] = h0[i];
    if (tid < 24) {
        bb[tid]  = bhh[8 * b + tid / 3 + (tid % 3) * H_DIM];
        gxs[tid] = gx[b * 24 + tid];   // step-0 input gates (permuted layout)
    }
    __syncthreads();

    const int rbase = w * 6;
    for (int t = 0; t < S_SEQ; ++t) {
        // Prefetch next step's 24 gx values (coalesced 96B per block).
        float gpre = 0.f;
        const bool pf = (tid < 24) && (t + 1 < S_SEQ);
        if (pf) gpre = gx[(size_t)(t + 1) * H3 + b * 24 + tid];

        // h chunk into registers: lane l covers k in [i*512 + l*8, +8).
        float4 hreg[8];
        const float4* hs4 = (const float4*)hs;
        #pragma unroll
        for (int i = 0; i < 4; ++i) {
            hreg[i * 2 + 0] = hs4[i * 128 + l * 2 + 0];
            hreg[i * 2 + 1] = hs4[i * 128 + l * 2 + 1];
        }

        // 6 row dots (bf16 weights, fp32 accumulate), full-wave butterfly.
        float sums[6];
        #pragma unroll
        for (int m = 0; m < 6; ++m) {
            const int r = rbase + m;
            const uint4* wrow = (const uint4*)wlds + r * 256;
            float a0 = 0.f, a1 = 0.f, a2 = 0.f, a3 = 0.f;
            #pragma unroll
            for (int i = 0; i < 4; ++i) {
                const uint4 u = wrow[i * 64 + l];
                const float4 hv0 = hreg[i * 2 + 0], hv1 = hreg[i * 2 + 1];
                a0 += __uint_as_float(u.x << 16)          * hv0.x;
                a1 += __uint_as_float(u.x & 0xffff0000u)  * hv0.y;
                a2 += __uint_as_float(u.y << 16)          * hv0.z;
                a3 += __uint_as_float(u.y & 0xffff0000u)  * hv0.w;
                a0 += __uint_as_float(u.z << 16)          * hv1.x;
                a1 += __uint_as_float(u.z & 0xffff0000u)  * hv1.y;
                a2 += __uint_as_float(u.w << 16)          * hv1.z;
                a3 += __uint_as_float(u.w & 0xffff0000u)  * hv1.w;
            }
            float acc = (a0 + a1) + (a2 + a3);
            #pragma unroll
            for (int off = 32; off; off >>= 1) acc += __shfl_xor(acc, off);
            sums[m] = acc;
        }

        // Gate math: lane 0 -> unit 2w, lane 1 -> unit 2w+1.
        const int p = t & 1;
        const int cur = p * 32;
        if (l < 2) {
            const int jj = 2 * w + l;          // local unit 0..7
            const int mb = l * 3;
            const float h_r = sums[mb + 0] + bb[jj * 3 + 0];
            const float h_i = sums[mb + 1] + bb[jj * 3 + 1];
            const float h_n = sums[mb + 2] + bb[jj * 3 + 2];
            const float i_r = gxs[cur + jj * 3 + 0];
            const float i_i = gxs[cur + jj * 3 + 1];
            const float i_n = gxs[cur + jj * 3 + 2];
            const float rg = 1.f / (1.f + expf(-(i_r + h_r)));
            const float ig = 1.f / (1.f + expf(-(i_i + h_i)));
            const float ng = tanhf(i_n + rg * h_n);
            const int J = 8 * b + jj;
            const float hnew = ng + ig * (hs[J] - ng);
            log_h[(size_t)t * H_DIM + J] = hnew;            // plain store (output)
            // Data-carrying slot: 4B into own 64B line, MALL-direct.
            __hip_atomic_store((float*)&bar[((p << 8) + b) * 16 + jj], hnew,
                               __ATOMIC_RELAXED, __HIP_MEMORY_SCOPE_AGENT);
        }

        if (t == S_SEQ - 1) break;

        const unsigned tgt = (unsigned)(t + 1);
        __syncthreads();   // every wave drains vmcnt -> slot h stores ack'd
        if (tid == 0)
            __hip_atomic_store(&bar[((p << 8) + b) * 16 + 8], tgt,
                               __ATOMIC_RELAXED, __HIP_MEMORY_SCOPE_AGENT);

        // Flat all-to-all: poll one slot, pull its 8 h values into LDS.
        {
            const int s = (tid + b) & 255;
            unsigned* sl = &bar[((p << 8) + s) * 16];
            while (__hip_atomic_load(&sl[8], __ATOMIC_RELAXED,
                                     __HIP_MEMORY_SCOPE_AGENT) < tgt) {}
            asm volatile("" ::: "memory");
            const float v0 = __hip_atomic_load((const float*)&sl[0], __ATOMIC_RELAXED, __HIP_MEMORY_SCOPE_AGENT);
            const float v1 = __hip_atomic_load((const float*)&sl[1], __ATOMIC_RELAXED, __HIP_MEMORY_SCOPE_AGENT);
            const float v2 = __hip_atomic_load((const float*)&sl[2], __ATOMIC_RELAXED, __HIP_MEMORY_SCOPE_AGENT);
            const float v3 = __hip_atomic_load((const float*)&sl[3], __ATOMIC_RELAXED, __HIP_MEMORY_SCOPE_AGENT);
            const float v4 = __hip_atomic_load((const float*)&sl[4], __ATOMIC_RELAXED, __HIP_MEMORY_SCOPE_AGENT);
            const float v5 = __hip_atomic_load((const float*)&sl[5], __ATOMIC_RELAXED, __HIP_MEMORY_SCOPE_AGENT);
            const float v6 = __hip_atomic_load((const float*)&sl[6], __ATOMIC_RELAXED, __HIP_MEMORY_SCOPE_AGENT);
            const float v7 = __hip_atomic_load((const float*)&sl[7], __ATOMIC_RELAXED, __HIP_MEMORY_SCOPE_AGENT);
            float4* hd = (float4*)hs;
            hd[s * 2 + 0] = make_float4(v0, v1, v2, v3);
            hd[s * 2 + 1] = make_float4(v4, v5, v6, v7);
        }
        if (pf) gxs[(~t & 1) * 32 + tid] = gpre;
        __syncthreads();
    }
}

// ---------------------------------------------------------------------------
// Fallback per-step kernel (round-1 path). permGx: gx in [t][block][24] layout.
// ---------------------------------------------------------------------------
__global__ __launch_bounds__(192) void gru_step(
    const float* __restrict__ Whh, const float* __restrict__ bhh,
    const float* __restrict__ gx_t,
    const float* __restrict__ Wih, const float* __restrict__ bih,
    const float* __restrict__ X, int t, int permGx,
    const float* __restrict__ h_prev, float* __restrict__ h_out)
{
    __shared__ __align__(16) float hsl[H_DIM];
    __shared__ float red[3], gred[3];
    const int tid = threadIdx.x;
    for (int i = tid; i < H_DIM; i += 192) hsl[i] = h_prev[i];
    __syncthreads();

    const int w = tid >> 6, lane = tid & 63;
    const int j = blockIdx.x;
    const int row = j + w * H_DIM;

    const float4* Wr = (const float4*)(Whh + (size_t)row * H_DIM);
    const float4* h4 = (const float4*)hsl;
    float acc = 0.f;
    #pragma unroll
    for (int k = 0; k < H_DIM / 256; ++k) {
        const float4 wv = Wr[lane + 64 * k];
        const float4 hv = h4[lane + 64 * k];
        acc += wv.x * hv.x + wv.y * hv.y + wv.z * hv.z + wv.w * hv.w;
    }
    float gacc = 0.f;
    if (gx_t == nullptr) {
        const float* Wi = Wih + (size_t)row * D_IN;
        #pragma unroll
        for (int k = 0; k < D_IN / 64; ++k) {
            const int d = lane + 64 * k;
            gacc += Wi[d] * X[(size_t)d * T_SEQ + t];
        }
    }
    #pragma unroll
    for (int off = 32; off > 0; off >>= 1) {
        acc  += __shfl_xor(acc, off);
        gacc += __shfl_xor(gacc, off);
    }
    if (lane == 0) {
        red[w]  = acc + bhh[row];
        gred[w] = gacc + ((gx_t == nullptr) ? bih[row] : 0.f);
    }
    __syncthreads();
    if (tid == 0) {
        float i_r, i_i, i_n;
        if (gx_t) {
            if (permGx) {
                const int base = (j >> 3) * 24 + (j & 7) * 3;
                i_r = gx_t[base]; i_i = gx_t[base + 1]; i_n = gx_t[base + 2];
            } else {
                i_r = gx_t[j]; i_i = gx_t[j + H_DIM]; i_n = gx_t[j + 2 * H_DIM];
            }
        } else { i_r = gred[0]; i_i = gred[1]; i_n = gred[2]; }
        const float h_r = red[0], h_i = red[1], h_n = red[2];
        const float rg = 1.f / (1.f + expf(-(i_r + h_r)));
        const float ig = 1.f / (1.f + expf(-(i_i + h_i)));
        const float ng = tanhf(i_n + rg * h_n);
        h_out[j] = ng + ig * (hsl[j] - ng);
    }
}

// ---------------------------------------------------------------------------
// Per-step loss + Pearson correlation.
// ---------------------------------------------------------------------------
__global__ __launch_bounds__(256) void loss_acc(
    const float* __restrict__ X, const float* __restrict__ yhat_all,
    float* __restrict__ log_loss, float* __restrict__ log_acc)
{
    const int t = blockIdx.x;
    const float* yh = yhat_all + (size_t)t * D_IN;
    const int tid = threadIdx.x;
    float s_y = 0, s_p = 0, s_yy = 0, s_pp = 0, s_yp = 0, s_d2 = 0;
    for (int d = tid; d < D_IN; d += 256) {
        const float y = X[(size_t)d * T_SEQ + (t + 1)];
        const float p = yh[d];
        const float df = y - p;
        s_y += y; s_p += p; s_yy += y * y; s_pp += p * p; s_yp += y * p; s_d2 += df * df;
    }
    #pragma unroll
    for (int off = 32; off > 0; off >>= 1) {
        s_y  += __shfl_xor(s_y, off);  s_p  += __shfl_xor(s_p, off);
        s_yy += __shfl_xor(s_yy, off); s_pp += __shfl_xor(s_pp, off);
        s_yp += __shfl_xor(s_yp, off); s_d2 += __shfl_xor(s_d2, off);
    }
    __shared__ float red[4][6];
    const int w = tid >> 6;
    if ((tid & 63) == 0) {
        red[w][0] = s_y; red[w][1] = s_p; red[w][2] = s_yy;
        red[w][3] = s_pp; red[w][4] = s_yp; red[w][5] = s_d2;
    }
    __syncthreads();
    if (tid == 0) {
        float a = 0, b = 0, cc = 0, dd = 0, e = 0, f = 0;
        for (int i = 0; i < 4; ++i) {
            a += red[i][0]; b += red[i][1]; cc += red[i][2];
            dd += red[i][3]; e += red[i][4]; f += red[i][5];
        }
        const float n = (float)D_IN;
        log_loss[t] = f / n;
        const float cov = e - a * b / n;
        const float vy  = cc - a * a / n;
        const float vp  = dd - b * b / n;
        log_acc[t] = cov / (sqrtf(vy) * sqrtf(vp));
    }
}

__global__ __launch_bounds__(256) void loss_sum(
    const float* __restrict__ log_loss, float* __restrict__ out)
{
    float s = 0;
    for (int i = threadIdx.x; i < S_SEQ; i += 256) s += log_loss[i];
    #pragma unroll
    for (int off = 32; off > 0; off >>= 1) s += __shfl_xor(s, off);
    __shared__ float red[4];
    if ((threadIdx.x & 63) == 0) red[threadIdx.x >> 6] = s;
    __syncthreads();
    if (threadIdx.x == 0) out[0] = red[0] + red[1] + red[2] + red[3];
}

// ---------------------------------------------------------------------------
extern "C" void kernel_launch(void* const* d_in, const int* in_sizes, int n_in,
                              void* d_out, int out_size, void* d_ws, size_t ws_size,
                              hipStream_t stream)
{
    const float* X   = (const float*)d_in[0];
    const float* h0  = (const float*)d_in[1];
    const float* Wih = (const float*)d_in[2];
    const float* bih = (const float*)d_in[3];
    const float* Whh = (const float*)d_in[4];
    const float* bhh = (const float*)d_in[5];
    const float* Who = (const float*)d_in[6];
    const float* bho = (const float*)d_in[7];

    float* out       = (float*)d_out;
    float* loss_out  = out;                               // [1]
    float* log_loss  = out + 1;                           // [4095]
    float* log_acc   = out + 1 + S_SEQ;                   // [4095]
    float* log_h     = out + 1 + 2 * S_SEQ;               // [4095*2048]
    float* log_yhat  = log_h + (size_t)S_SEQ * H_DIM;     // [4095*1024]

    const size_t wbf_bytes = (size_t)256 * 24 * 2048 * sizeof(unsigned short); // 24 MB
    const size_t gx_bytes  = (size_t)S_SEQ * H3 * sizeof(float);               // ~96 MB
    const size_t bar_bytes = 2 * 256 * 64;                                     // 32 KB

    const bool full = (ws_size >= wbf_bytes + gx_bytes + bar_bytes);
    unsigned short* wbf = full ? (unsigned short*)d_ws : nullptr;
    float* gx = full ? (float*)((char*)d_ws + wbf_bytes)
                     : ((ws_size >= gx_bytes) ? (float*)d_ws : nullptr);
    unsigned* bar = full ? (unsigned*)((char*)d_ws + wbf_bytes + gx_bytes) : nullptr;

    // Phase 1: gx_all = x_seq @ W_i2h^T + b_i2h (permuted to [t][block][24]
    // when the cooperative path is available).
    if (gx) {
        dim3 g((S_SEQ + TS - 1) / TS, H3 / TS);
        gemm_bias<<<g, 256, 0, stream>>>(X, Wih, bih, gx, S_SEQ, H3, D_IN, T_SEQ, 1,
                                         full ? 1 : 0);
    }

    // Phase 2: sequential scan.
    bool coop_ok = false;
    if (full) {
        hipMemsetAsync(bar, 0, bar_bytes, stream);        // deterministic barrier state
        conv_whh<<<12288, 256, 0, stream>>>(Whh, wbf);
        hipFuncSetAttribute(reinterpret_cast<const void*>(gru_scan),
                            hipFuncAttributeMaxDynamicSharedMemorySize, SMEM_SZ);
        void* args[] = {(void*)&wbf, (void*)&bhh, (void*)&gx, (void*)&h0,
                        (void*)&log_h, (void*)&bar};
        hipError_t ce = hipLaunchCooperativeKernel(
            reinterpret_cast<const void*>(gru_scan), dim3(256), dim3(256),
            args, (unsigned int)SMEM_SZ, stream);
        coop_ok = (ce == hipSuccess);
    }
    if (!coop_ok) {
        for (int t = 0; t < S_SEQ; ++t) {
            const float* hp = (t == 0) ? h0 : (log_h + (size_t)(t - 1) * H_DIM);
            gru_step<<<H_DIM, 192, 0, stream>>>(
                Whh, bhh, gx ? gx + (size_t)t * H3 : nullptr,
                Wih, bih, X, t, full ? 1 : 0, hp, log_h + (size_t)t * H_DIM);
        }
    }

    // Phase 3: log_yhat = log_h @ W_h2o^T + b_h2o
    {
        dim3 g((S_SEQ + TS - 1) / TS, D_IN / TS);
        gemm_bias<<<g, 256, 0, stream>>>(log_h, Who, bho, log_yhat, S_SEQ, D_IN, H_DIM, H_DIM, 0, 0);
    }

    // Phase 4: per-step loss + Pearson corr, then total loss.
    loss_acc<<<S_SEQ, 256, 0, stream>>>(X, log_yhat, log_loss, log_acc);
    loss_sum<<<1, 256, 0, stream>>>(log_loss, loss_out);
}

// Round 6
// 24793.925 us; speedup vs baseline: 7.9991x; 1.0322x over previous
//
#include <hip/hip_runtime.h>
#include <math.h>

#define D_IN  1024
#define H_DIM 2048
#define H3    6144
#define T_SEQ 4096
#define S_SEQ 4095

// ---------------------------------------------------------------------------
// Tiled fp32 GEMM: C[M,N] = op(A)[M,K] @ B[N,K]^T + bias[N]
//   Atrans=1: A(m,k) = A[k*lda + m]   (gx: A = X, lda = T)
//   Atrans=0: A(m,k) = A[m*lda + k]   (yhat: A = log_h, lda = H)
// ---------------------------------------------------------------------------
#define TS 64
#define KS 16
#define LSTR 68

__global__ __launch_bounds__(256) void gemm_bias(
    const float* __restrict__ A, const float* __restrict__ B,
    const float* __restrict__ bias, float* __restrict__ C,
    int M, int N, int K, int lda, int Atrans)
{
    __shared__ __align__(16) float As[KS * LSTR];
    __shared__ __align__(16) float Bs[KS * LSTR];
    const int tid = threadIdx.x;
    const int m0 = blockIdx.x * TS;
    const int n0 = blockIdx.y * TS;
    const int tx = tid & 15, ty = tid >> 4;
    float c[4][4] = {};

    for (int k0 = 0; k0 < K; k0 += KS) {
        if (Atrans) {
            const int ml = tid & 63;
            const int kb = tid >> 6;
            #pragma unroll
            for (int kk = 0; kk < KS; kk += 4) {
                const int m = m0 + ml;
                As[(kk + kb) * LSTR + ml] =
                    (m < M) ? A[(size_t)(k0 + kk + kb) * lda + m] : 0.f;
            }
        } else {
            const int kl = tid & 15;
            const int mb = tid >> 4;
            #pragma unroll
            for (int ml = 0; ml < TS; ml += 16) {
                const int m = m0 + ml + mb;
                As[kl * LSTR + ml + mb] =
                    (m < M) ? A[(size_t)m * lda + (k0 + kl)] : 0.f;
            }
        }
        {
            const int kl = tid & 15;
            const int nb = tid >> 4;
            #pragma unroll
            for (int nl = 0; nl < TS; nl += 16) {
                Bs[kl * LSTR + nl + nb] = B[(size_t)(n0 + nl + nb) * K + (k0 + kl)];
            }
        }
        __syncthreads();
        #pragma unroll
        for (int kk = 0; kk < KS; ++kk) {
            const float4 a = *(const float4*)&As[kk * LSTR + tx * 4];
            const float4 b = *(const float4*)&Bs[kk * LSTR + ty * 4];
            c[0][0] += a.x * b.x; c[0][1] += a.x * b.y; c[0][2] += a.x * b.z; c[0][3] += a.x * b.w;
            c[1][0] += a.y * b.x; c[1][1] += a.y * b.y; c[1][2] += a.y * b.z; c[1][3] += a.y * b.w;
            c[2][0] += a.z * b.x; c[2][1] += a.z * b.y; c[2][2] += a.z * b.z; c[2][3] += a.z * b.w;
            c[3][0] += a.w * b.x; c[3][1] += a.w * b.y; c[3][2] += a.w * b.z; c[3][3] += a.w * b.w;
        }
        __syncthreads();
    }
    #pragma unroll
    for (int i = 0; i < 4; ++i) {
        const int m = m0 + tx * 4 + i;
        if (m < M) {
            #pragma unroll
            for (int j = 0; j < 4; ++j) {
                const int n = n0 + ty * 4 + j;
                C[(size_t)m * N + n] = c[i][j] + bias[n];
            }
        }
    }
}

// ---------------------------------------------------------------------------
// Convert W_h2h (fp32, [6144,2048] gate-major) to bf16, re-laid-out so that
// block b's 24 rows (units 8b..8b+7, r = jj*3+g -> global row 8b+jj+g*2048)
// are contiguous: wbf[((b*24 + r)*2048) + k].
// ---------------------------------------------------------------------------
__device__ inline unsigned short f2bf(float f) {
    union { float f; unsigned u; } a; a.f = f;
    unsigned u = a.u;
    u += 0x7fffu + ((u >> 16) & 1u);   // round-to-nearest-even
    return (unsigned short)(u >> 16);
}

__global__ __launch_bounds__(256) void conv_whh(
    const float* __restrict__ Whh, unsigned short* __restrict__ wbf)
{
    const int g = blockIdx.x * 256 + threadIdx.x;
    const size_t base = (size_t)g * 4;              // 4 elems per thread
    const int b   = (int)(base / 49152);            // 24*2048
    const int rem = (int)(base % 49152);
    const int r   = rem / 2048;
    const int k   = rem % 2048;
    const size_t srow = ((size_t)(8 * b + r / 3 + (r % 3) * H_DIM)) * H_DIM + k;
    const float4 v = *(const float4*)(Whh + srow);
    ushort4 o;
    o.x = f2bf(v.x); o.y = f2bf(v.y); o.z = f2bf(v.z); o.w = f2bf(v.w);
    *(ushort4*)(wbf + base) = o;
}

// ---------------------------------------------------------------------------
// Persistent cooperative scan. 256 blocks x 256 threads, 1 block/CU.
// Block b owns units 8b..8b+7 (3 bf16 gate rows each, resident in LDS).
//
// h broadcast: DATA=FLAG packed words, one dependent MALL hop per step.
//   word = (bf16(h_new) << 16) | (t+1)     (tag in low 16 bits, t+1 <= 4094)
// Writer lane publishes its word immediately after gate math -- no block
// barrier, no vmcnt drain, no separate tag store (data+tag atomic in 4B).
// Reader thread polls its 8 words (stagger (tid+b)&255) with an equality
// check on the tag, then expands bf16 -> fp32 into LDS hs.
// Parity double-buffer (2 x 2048 words): the step-dependency chain proves
// parity-p words are never overwritten (t -> t+2) before every block has
// finished reading them, so the equality poll cannot deadlock.
// ---------------------------------------------------------------------------
#define SMEM_SZ (24 * 2048 * 2 + 2048 * 4 + 96 * 4)

__global__ __launch_bounds__(256, 1) void gru_scan(
    const unsigned short* __restrict__ wbf, const float* __restrict__ bhh,
    const float* __restrict__ gx, const float* __restrict__ h0,
    float* __restrict__ log_h, unsigned* __restrict__ pbuf)
{
    extern __shared__ char smem[];
    unsigned short* wlds = (unsigned short*)smem;            // 24*2048 bf16
    float* hs  = (float*)(smem + 24 * 2048 * 2);             // 2048 fp32
    float* gxs = (float*)(smem + 24 * 2048 * 2 + 2048 * 4);  // 2 x 32
    float* bb  = gxs + 64;                                   // 24

    const int tid = threadIdx.x;
    const int b = blockIdx.x;
    const int w = tid >> 6, l = tid & 63;
    const int s = (tid + b) & 255;          // slot group this thread fills

    // Stage this block's weight slice into LDS (96 KB, coalesced 16B/lane).
    {
        const uint4* src = (const uint4*)(wbf + (size_t)b * 24 * 2048);
        uint4* dst = (uint4*)wlds;
        #pragma unroll
        for (int i = 0; i < 24; ++i) dst[tid + 256 * i] = src[tid + 256 * i];
    }
    for (int i = tid; i < H_DIM; i += 256) hs[i] = h0[i];
    if (tid < 24) {
        const int n = 8 * b + tid / 3 + (tid % 3) * H_DIM;
        bb[tid]  = bhh[n];
        gxs[tid] = gx[n];              // step-0 input gates (includes b_i2h)
    }
    __syncthreads();

    const int rbase = w * 6;
    for (int t = 0; t < S_SEQ; ++t) {
        // Prefetch next step's 24 gx values (consumed after the fill phase).
        float gpre = 0.f;
        const bool pf = (tid < 24) && (t + 1 < S_SEQ);
        if (pf) gpre = gx[(size_t)(t + 1) * H3 + 8 * b + tid / 3 + (tid % 3) * H_DIM];

        // h chunk into registers: lane l covers k in [i*512 + l*8, +8).
        float4 hreg[8];
        const float4* hs4 = (const float4*)hs;
        #pragma unroll
        for (int i = 0; i < 4; ++i) {
            hreg[i * 2 + 0] = hs4[i * 128 + l * 2 + 0];
            hreg[i * 2 + 1] = hs4[i * 128 + l * 2 + 1];
        }

        // 6 row dots (bf16 weights, fp32 accumulate), full-wave butterfly.
        float sums[6];
        #pragma unroll
        for (int m = 0; m < 6; ++m) {
            const int r = rbase + m;
            const uint4* wrow = (const uint4*)wlds + r * 256;
            float a0 = 0.f, a1 = 0.f, a2 = 0.f, a3 = 0.f;
            #pragma unroll
            for (int i = 0; i < 4; ++i) {
                const uint4 u = wrow[i * 64 + l];
                const float4 hv0 = hreg[i * 2 + 0], hv1 = hreg[i * 2 + 1];
                a0 += __uint_as_float(u.x << 16)          * hv0.x;
                a1 += __uint_as_float(u.x & 0xffff0000u)  * hv0.y;
                a2 += __uint_as_float(u.y << 16)          * hv0.z;
                a3 += __uint_as_float(u.y & 0xffff0000u)  * hv0.w;
                a0 += __uint_as_float(u.z << 16)          * hv1.x;
                a1 += __uint_as_float(u.z & 0xffff0000u)  * hv1.y;
                a2 += __uint_as_float(u.w << 16)          * hv1.z;
                a3 += __uint_as_float(u.w & 0xffff0000u)  * hv1.w;
            }
            float acc = (a0 + a1) + (a2 + a3);
            #pragma unroll
            for (int off = 32; off; off >>= 1) acc += __shfl_xor(acc, off);
            sums[m] = acc;
        }

        // Gate math + IMMEDIATE publish (data=flag packed word, 1 store).
        const int p = t & 1;
        const int cur = p * 32;
        if (l < 2) {
            const int jj = 2 * w + l;          // local unit 0..7
            const int mb = l * 3;
            const float h_r = sums[mb + 0] + bb[jj * 3 + 0];
            const float h_i = sums[mb + 1] + bb[jj * 3 + 1];
            const float h_n = sums[mb + 2] + bb[jj * 3 + 2];
            const float i_r = gxs[cur + jj * 3 + 0];
            const float i_i = gxs[cur + jj * 3 + 1];
            const float i_n = gxs[cur + jj * 3 + 2];
            const float rg = 1.f / (1.f + expf(-(i_r + h_r)));
            const float ig = 1.f / (1.f + expf(-(i_i + h_i)));
            const float ng = tanhf(i_n + rg * h_n);
            const int J = 8 * b + jj;
            const float hnew = ng + ig * (hs[J] - ng);
            const unsigned hb = (unsigned)f2bf(hnew) << 16;   // bf16 in hi bits
            if (t + 1 < S_SEQ)
                __hip_atomic_store(&pbuf[(p << 11) + J], hb | (unsigned)(t + 1),
                                   __ATOMIC_RELAXED, __HIP_MEMORY_SCOPE_AGENT);
            log_h[(size_t)t * H_DIM + J] = __uint_as_float(hb);  // rounded, consistent
        }

        if (t == S_SEQ - 1) break;

        __syncthreads();   // all waves finished reading hs (hreg + hs[J])

        // Fill phase: poll own 8 packed words, expand into hs.
        {
            const unsigned want = (unsigned)(t + 1);
            unsigned* basep = pbuf + (p << 11) + s * 8;
            unsigned v0, v1, v2, v3, v4, v5, v6, v7;
            for (;;) {
                v0 = __hip_atomic_load(&basep[0], __ATOMIC_RELAXED, __HIP_MEMORY_SCOPE_AGENT);
                v1 = __hip_atomic_load(&basep[1], __ATOMIC_RELAXED, __HIP_MEMORY_SCOPE_AGENT);
                v2 = __hip_atomic_load(&basep[2], __ATOMIC_RELAXED, __HIP_MEMORY_SCOPE_AGENT);
                v3 = __hip_atomic_load(&basep[3], __ATOMIC_RELAXED, __HIP_MEMORY_SCOPE_AGENT);
                v4 = __hip_atomic_load(&basep[4], __ATOMIC_RELAXED, __HIP_MEMORY_SCOPE_AGENT);
                v5 = __hip_atomic_load(&basep[5], __ATOMIC_RELAXED, __HIP_MEMORY_SCOPE_AGENT);
                v6 = __hip_atomic_load(&basep[6], __ATOMIC_RELAXED, __HIP_MEMORY_SCOPE_AGENT);
                v7 = __hip_atomic_load(&basep[7], __ATOMIC_RELAXED, __HIP_MEMORY_SCOPE_AGENT);
                const unsigned mism =
                    ((v0 ^ want) | (v1 ^ want) | (v2 ^ want) | (v3 ^ want) |
                     (v4 ^ want) | (v5 ^ want) | (v6 ^ want) | (v7 ^ want)) & 0xffffu;
                if (mism == 0) break;
            }
            float* hd = hs + s * 8;
            hd[0] = __uint_as_float(v0 & 0xffff0000u);
            hd[1] = __uint_as_float(v1 & 0xffff0000u);
            hd[2] = __uint_as_float(v2 & 0xffff0000u);
            hd[3] = __uint_as_float(v3 & 0xffff0000u);
            hd[4] = __uint_as_float(v4 & 0xffff0000u);
            hd[5] = __uint_as_float(v5 & 0xffff0000u);
            hd[6] = __uint_as_float(v6 & 0xffff0000u);
            hd[7] = __uint_as_float(v7 & 0xffff0000u);
        }
        if (pf) gxs[(~t & 1) * 32 + tid] = gpre;
        __syncthreads();
    }
}

// ---------------------------------------------------------------------------
// Fallback per-step kernel (round-1 path).
// ---------------------------------------------------------------------------
__global__ __launch_bounds__(192) void gru_step(
    const float* __restrict__ Whh, const float* __restrict__ bhh,
    const float* __restrict__ gx_t,
    const float* __restrict__ Wih, const float* __restrict__ bih,
    const float* __restrict__ X, int t,
    const float* __restrict__ h_prev, float* __restrict__ h_out)
{
    __shared__ __align__(16) float hsl[H_DIM];
    __shared__ float red[3], gred[3];
    const int tid = threadIdx.x;
    for (int i = tid; i < H_DIM; i += 192) hsl[i] = h_prev[i];
    __syncthreads();

    const int w = tid >> 6, lane = tid & 63;
    const int j = blockIdx.x;
    const int row = j + w * H_DIM;

    const float4* Wr = (const float4*)(Whh + (size_t)row * H_DIM);
    const float4* h4 = (const float4*)hsl;
    float acc = 0.f;
    #pragma unroll
    for (int k = 0; k < H_DIM / 256; ++k) {
        const float4 wv = Wr[lane + 64 * k];
        const float4 hv = h4[lane + 64 * k];
        acc += wv.x * hv.x + wv.y * hv.y + wv.z * hv.z + wv.w * hv.w;
    }
    float gacc = 0.f;
    if (gx_t == nullptr) {
        const float* Wi = Wih + (size_t)row * D_IN;
        #pragma unroll
        for (int k = 0; k < D_IN / 64; ++k) {
            const int d = lane + 64 * k;
            gacc += Wi[d] * X[(size_t)d * T_SEQ + t];
        }
    }
    #pragma unroll
    for (int off = 32; off > 0; off >>= 1) {
        acc  += __shfl_xor(acc, off);
        gacc += __shfl_xor(gacc, off);
    }
    if (lane == 0) {
        red[w]  = acc + bhh[row];
        gred[w] = gacc + ((gx_t == nullptr) ? bih[row] : 0.f);
    }
    __syncthreads();
    if (tid == 0) {
        float i_r, i_i, i_n;
        if (gx_t) { i_r = gx_t[j]; i_i = gx_t[j + H_DIM]; i_n = gx_t[j + 2 * H_DIM]; }
        else      { i_r = gred[0]; i_i = gred[1]; i_n = gred[2]; }
        const float h_r = red[0], h_i = red[1], h_n = red[2];
        const float rg = 1.f / (1.f + expf(-(i_r + h_r)));
        const float ig = 1.f / (1.f + expf(-(i_i + h_i)));
        const float ng = tanhf(i_n + rg * h_n);
        h_out[j] = ng + ig * (hsl[j] - ng);
    }
}

// ---------------------------------------------------------------------------
// Per-step loss + Pearson correlation.
// ---------------------------------------------------------------------------
__global__ __launch_bounds__(256) void loss_acc(
    const float* __restrict__ X, const float* __restrict__ yhat_all,
    float* __restrict__ log_loss, float* __restrict__ log_acc)
{
    const int t = blockIdx.x;
    const float* yh = yhat_all + (size_t)t * D_IN;
    const int tid = threadIdx.x;
    float s_y = 0, s_p = 0, s_yy = 0, s_pp = 0, s_yp = 0, s_d2 = 0;
    for (int d = tid; d < D_IN; d += 256) {
        const float y = X[(size_t)d * T_SEQ + (t + 1)];
        const float p = yh[d];
        const float df = y - p;
        s_y += y; s_p += p; s_yy += y * y; s_pp += p * p; s_yp += y * p; s_d2 += df * df;
    }
    #pragma unroll
    for (int off = 32; off > 0; off >>= 1) {
        s_y  += __shfl_xor(s_y, off);  s_p  += __shfl_xor(s_p, off);
        s_yy += __shfl_xor(s_yy, off); s_pp += __shfl_xor(s_pp, off);
        s_yp += __shfl_xor(s_yp, off); s_d2 += __shfl_xor(s_d2, off);
    }
    __shared__ float red[4][6];
    const int w = tid >> 6;
    if ((tid & 63) == 0) {
        red[w][0] = s_y; red[w][1] = s_p; red[w][2] = s_yy;
        red[w][3] = s_pp; red[w][4] = s_yp; red[w][5] = s_d2;
    }
    __syncthreads();
    if (tid == 0) {
        float a = 0, b = 0, cc = 0, dd = 0, e = 0, f = 0;
        for (int i = 0; i < 4; ++i) {
            a += red[i][0]; b += red[i][1]; cc += red[i][2];
            dd += red[i][3]; e += red[i][4]; f += red[i][5];
        }
        const float n = (float)D_IN;
        log_loss[t] = f / n;
        const float cov = e - a * b / n;
        const float vy  = cc - a * a / n;
        const float vp  = dd - b * b / n;
        log_acc[t] = cov / (sqrtf(vy) * sqrtf(vp));
    }
}

__global__ __launch_bounds__(256) void loss_sum(
    const float* __restrict__ log_loss, float* __restrict__ out)
{
    float s = 0;
    for (int i = threadIdx.x; i < S_SEQ; i += 256) s += log_loss[i];
    #pragma unroll
    for (int off = 32; off > 0; off >>= 1) s += __shfl_xor(s, off);
    __shared__ float red[4];
    if ((threadIdx.x & 63) == 0) red[threadIdx.x >> 6] = s;
    __syncthreads();
    if (threadIdx.x == 0) out[0] = red[0] + red[1] + red[2] + red[3];
}

// ---------------------------------------------------------------------------
extern "C" void kernel_launch(void* const* d_in, const int* in_sizes, int n_in,
                              void* d_out, int out_size, void* d_ws, size_t ws_size,
                              hipStream_t stream)
{
    const float* X   = (const float*)d_in[0];
    const float* h0  = (const float*)d_in[1];
    const float* Wih = (const float*)d_in[2];
    const float* bih = (const float*)d_in[3];
    const float* Whh = (const float*)d_in[4];
    const float* bhh = (const float*)d_in[5];
    const float* Who = (const float*)d_in[6];
    const float* bho = (const float*)d_in[7];

    float* out       = (float*)d_out;
    float* loss_out  = out;                               // [1]
    float* log_loss  = out + 1;                           // [4095]
    float* log_acc   = out + 1 + S_SEQ;                   // [4095]
    float* log_h     = out + 1 + 2 * S_SEQ;               // [4095*2048]
    float* log_yhat  = log_h + (size_t)S_SEQ * H_DIM;     // [4095*1024]

    const size_t wbf_bytes = (size_t)256 * 24 * 2048 * sizeof(unsigned short); // 24 MB
    const size_t gx_bytes  = (size_t)S_SEQ * H3 * sizeof(float);               // ~96 MB
    const size_t bar_bytes = 2 * 2048 * sizeof(unsigned);                      // 16 KB

    const bool full = (ws_size >= wbf_bytes + gx_bytes + bar_bytes);
    unsigned short* wbf = full ? (unsigned short*)d_ws : nullptr;
    float* gx = full ? (float*)((char*)d_ws + wbf_bytes)
                     : ((ws_size >= gx_bytes) ? (float*)d_ws : nullptr);
    unsigned* pbuf = full ? (unsigned*)((char*)d_ws + wbf_bytes + gx_bytes) : nullptr;

    // Phase 1: gx_all = x_seq @ W_i2h^T + b_i2h  (parallel)
    if (gx) {
        dim3 g((S_SEQ + TS - 1) / TS, H3 / TS);
        gemm_bias<<<g, 256, 0, stream>>>(X, Wih, bih, gx, S_SEQ, H3, D_IN, T_SEQ, 1);
    }

    // Phase 2: sequential scan.
    bool coop_ok = false;
    if (full) {
        hipMemsetAsync(pbuf, 0, bar_bytes, stream);       // deterministic slot state
        conv_whh<<<12288, 256, 0, stream>>>(Whh, wbf);
        hipFuncSetAttribute(reinterpret_cast<const void*>(gru_scan),
                            hipFuncAttributeMaxDynamicSharedMemorySize, SMEM_SZ);
        void* args[] = {(void*)&wbf, (void*)&bhh, (void*)&gx, (void*)&h0,
                        (void*)&log_h, (void*)&pbuf};
        hipError_t ce = hipLaunchCooperativeKernel(
            reinterpret_cast<const void*>(gru_scan), dim3(256), dim3(256),
            args, (unsigned int)SMEM_SZ, stream);
        coop_ok = (ce == hipSuccess);
    }
    if (!coop_ok) {
        for (int t = 0; t < S_SEQ; ++t) {
            const float* hp = (t == 0) ? h0 : (log_h + (size_t)(t - 1) * H_DIM);
            gru_step<<<H_DIM, 192, 0, stream>>>(
                Whh, bhh, gx ? gx + (size_t)t * H3 : nullptr,
                Wih, bih, X, t, hp, log_h + (size_t)t * H_DIM);
        }
    }

    // Phase 3: log_yhat = log_h @ W_h2o^T + b_h2o
    {
        dim3 g((S_SEQ + TS - 1) / TS, D_IN / TS);
        gemm_bias<<<g, 256, 0, stream>>>(log_h, Who, bho, log_yhat, S_SEQ, D_IN, H_DIM, H_DIM, 0);
    }

    // Phase 4: per-step loss + Pearson corr, then total loss.
    loss_acc<<<S_SEQ, 256, 0, stream>>>(X, log_yhat, log_loss, log_acc);
    loss_sum<<<1, 256, 0, stream>>>(log_loss, loss_out);
}